// Round 6
// baseline (202.542 us; speedup 1.0000x reference)
//
#include <hip/hip_runtime.h>
#include <hip/hip_bf16.h>

// MoE MLP (top-2 of 8 experts), T=4096 tokens, D=1024, W=1024.
// R12: base = R10 (best passing, 188.8us). R11's cooperative mono-kernel
//      produced zeros (coop launch + graph capture don't mix) -- reverted.
//      One lever: fuse combine into gemm2's epilogue via fp32 atomics:
//        out[tok][col] += wslot[slot] * v   (exactly 2 addends/address,
//        bitwise-deterministic; unsafeAtomicAdd = global_atomic_add_f32).
//      Removes combine kernel + y buffer (16MB write + 32MB read); adds
//      16MB memset of out (~2.5us) + ~8.4M uncontended atomics.
//      build_lists emits wslot (per-slot routing weight) instead of tslot.
// Retained: 128x128 GEMM tile BK=64 granule-XOR swizzle, expert=bid&7 XCD map,
//           128x128 transposes (w2t fused into gemm1 grid), CAP=1536,
//           gload_lds w16 staging, ballot build_lists.

#define T_TOKENS 4096
#define DD 1024
#define EE 8
#define WW 1024
#define CAP 1536              // per-expert capacity (expected ~1024, sigma ~28)
#define BM 128
#define BN 128
#define BK 64
#define MT (CAP / BM)         // 12 m-tiles max per expert
#define NT (WW / BN)          // 8 n-tiles
#define GEMM_BLOCKS (EE * MT * NT)  // 768
#define TR1_BLOCKS 512        // w1 transpose blocks (128x128 tiles, in pre)
#define TR2_BLOCKS 512        // w2 transpose blocks (in gemm1 grid)
#define TLD 132               // LDS transpose tile row stride (shorts), pad=4

typedef short bf16x8 __attribute__((ext_vector_type(8)));
typedef float f32x4 __attribute__((ext_vector_type(4)));

__device__ __forceinline__ void gload_lds16(const void* g, void* l) {
  __builtin_amdgcn_global_load_lds((__attribute__((address_space(1))) void*)(g),
                                   (__attribute__((address_space(3))) void*)(l),
                                   16, 0, 0);
}

__device__ __forceinline__ float bf2f(unsigned short u) {
  union { unsigned int i; float f; } v; v.i = (unsigned int)u << 16; return v.f;
}

__device__ __forceinline__ unsigned short f2bf_u(float f) {
  __hip_bfloat16 h = __float2bfloat16(f);
  union { __hip_bfloat16 h; unsigned short u; } c; c.h = h; return c.u;
}

// ---- 128x128 fp32->bf16 transpose tile through LDS (R10-proven) ----
// dst[(c0+c)*dst_ld + r0 + r] = bf16(src[(r0+r)*src_ld + c0 + c])
__device__ __forceinline__ void transpose_tile_128(
    const float* __restrict__ src, long src_ld, long r0, long c0,
    unsigned short* __restrict__ dst, long dst_ld, unsigned short* lds)
{
  int tid = threadIdx.x;
  int cq = tid & 31;            // covers 4 src cols
  int rb = tid >> 5;            // row base 0..7
#pragma unroll
  for (int i = 0; i < 16; i++) {
    int r = rb + i * 8;
    f32x4 v = *(const f32x4*)(src + (r0 + r) * src_ld + c0 + cq * 4);
#pragma unroll
    for (int j = 0; j < 4; j++)
      lds[(cq * 4 + j) * TLD + r] = f2bf_u(v[j]);
  }
  __syncthreads();
#pragma unroll
  for (int it = 0; it < 8; it++) {
    int slot = it * 256 + tid;
    int c = slot >> 4;          // dst row within tile
    int m = slot & 15;          // 8-elem chunk within row
    const unsigned short* p = lds + (size_t)c * TLD + m * 8;
    uint2 lo = *(const uint2*)(p);
    uint2 hi = *(const uint2*)(p + 4);
    uint4 o; o.x = lo.x; o.y = lo.y; o.z = hi.x; o.w = hi.y;
    *(uint4*)(dst + (c0 + c) * dst_ld + r0 + m * 8) = o;
  }
}

// ---------------- pre: w1 transpose (128x128 tiles) + router ----------------
// blocks [0,512): w1 transpose; [512,1536): router, 1 wave = 1 token.
__global__ __launch_bounds__(256) void pre_kernel(
    const float* __restrict__ w1, const float* __restrict__ x,
    const float* __restrict__ rw,
    __hip_bfloat16* __restrict__ w1t, __hip_bfloat16* __restrict__ xb,
    int* __restrict__ sel, float* __restrict__ wpair)
{
  __shared__ unsigned short lds_t[128 * TLD];   // 33792 B
  int b = blockIdx.x;
  if (b < TR1_BLOCKS) {
    // w1 [D=1024, E*W=8192] -> w1t [8192, 1024] bf16
    int bn = b >> 3;            // n-tile 0..63 (src col / dst row)
    int bd = b & 7;             // d-tile 0..7  (src row / dst col)
    transpose_tile_128(w1, EE * WW, (long)bd * 128, (long)bn * 128,
                       (unsigned short*)w1t, DD, lds_t);
  } else {
    // router: one wave per token, fp32 logits, top-2, no atomics
    int lane = threadIdx.x & 63;
    int wave = threadIdx.x >> 6;
    int t = (b - TR1_BLOCKS) * 4 + wave;
    const float* xrow = x + (size_t)t * DD;
    float acc[EE];
#pragma unroll
    for (int e = 0; e < EE; e++) acc[e] = 0.f;
#pragma unroll
    for (int i = 0; i < DD / 64; i++) {
      int d = lane + i * 64;
      float xv = xrow[d];
      xb[t * DD + d] = __float2bfloat16(xv);   // fused x -> bf16
#pragma unroll
      for (int e = 0; e < EE; e++) acc[e] += xv * rw[e * DD + d];
    }
#pragma unroll
    for (int e = 0; e < EE; e++) {
#pragma unroll
      for (int off = 32; off > 0; off >>= 1)
        acc[e] += __shfl_down(acc[e], off, 64);
    }
    if (lane == 0) {
      float p[EE];
#pragma unroll
      for (int e = 0; e < EE; e++) p[e] = 1.f / (1.f + expf(-acc[e]));
      // top-2, ties -> lowest index (matches jax.lax.top_k stable ordering)
      int e0 = 0; float b0 = p[0];
      for (int e = 1; e < EE; e++) if (p[e] > b0) { b0 = p[e]; e0 = e; }
      int e1 = -1; float b1 = -1.f;
      for (int e = 0; e < EE; e++) {
        if (e == e0) continue;
        if (p[e] > b1) { b1 = p[e]; e1 = e; }
      }
      float s = b0 + b1 + 1e-20f;
      sel[t] = e0 | (e1 << 8);
      wpair[2 * t]     = b0 / s;
      wpair[2 * t + 1] = b1 / s;
    }
  }
}

// ---------------- build per-expert token lists (1 block, wave-ballot agg) ----
// Emits idx (slot -> token) and wslot (slot -> routing weight).
__global__ __launch_bounds__(1024) void build_lists(
    const int* __restrict__ sel, const float* __restrict__ wpair,
    int* __restrict__ counts, int* __restrict__ idx,
    float* __restrict__ wslot)
{
  __shared__ int lcnt[EE];
  int tid = threadIdx.x, lane = tid & 63;
  if (tid < EE) lcnt[tid] = 0;
  __syncthreads();
  unsigned long long lower = (1ull << lane) - 1;
#pragma unroll
  for (int j = 0; j < T_TOKENS / 1024; j++) {
    int t = j * 1024 + tid;
    int s = sel[t];
    int e0 = s & 0xff, e1 = (s >> 8) & 0xff;
    int slot0 = 0, slot1 = 0;
#pragma unroll
    for (int e = 0; e < EE; e++) {
      unsigned long long m0 = __ballot(e0 == e);
      unsigned long long m1 = __ballot(e1 == e);
      int c0 = __popcll(m0), c1 = __popcll(m1);
      int base = 0;
      if (lane == 0 && (c0 + c1) > 0) base = atomicAdd(&lcnt[e], c0 + c1);
      base = __shfl(base, 0, 64);
      if (e0 == e) slot0 = base + __popcll(m0 & lower);
      if (e1 == e) slot1 = base + c0 + __popcll(m1 & lower);
    }
    int p0 = e0 * CAP + slot0, p1 = e1 * CAP + slot1;
    idx[p0] = t; idx[p1] = t;
    wslot[p0] = wpair[2 * t];
    wslot[p1] = wpair[2 * t + 1];
  }
  __syncthreads();
  if (tid < EE) counts[tid] = lcnt[tid];
}

// ---------------- grouped GEMM1 (+ fused w2 transpose blocks) ----------------
// blocks [0,768): act = relu(gather(xb) @ W1_e)^2, 128x128 tile, BK=64.
// blocks [768, 768+512): w2 [E*W,D] -> w2t[e] [D,W] bf16, 128x128 tiles.
// XCD map: expert = bid & 7.
__global__ __launch_bounds__(256, 3) void gemm1_kernel(
    const __hip_bfloat16* __restrict__ xb, const __hip_bfloat16* __restrict__ w1t,
    const int* __restrict__ counts, const int* __restrict__ idx,
    __hip_bfloat16* __restrict__ act,
    const float* __restrict__ w2, __hip_bfloat16* __restrict__ w2t)
{
  __shared__ __attribute__((aligned(16))) char smem[128 * TLD * 2]; // 33792B
  int bid = blockIdx.x;
  if (bid >= GEMM_BLOCKS) {
    // ---- w2 transpose: expert slice [W,D] -> w2t[e] [D,W] ----
    int z = bid - GEMM_BLOCKS;      // 0..511
    int e = z >> 6;                 // 64 tiles per expert
    int t2 = z & 63;
    transpose_tile_128(w2 + (long)e * WW * DD, DD,
                       (long)(t2 >> 3) * 128, (long)(t2 & 7) * 128,
                       (unsigned short*)(w2t + (long)e * DD * WW), WW,
                       (unsigned short*)smem);
    return;
  }
  short* As = (short*)smem;
  short* Bs = (short*)(smem + 16384);
  int e = bid & 7;
  int i = bid >> 3;
  int mt = i >> 3, nt = i & 7;
  int n_e = counts[e];
  if (mt * BM >= n_e) return;

  int tid = threadIdx.x;
  int lane = tid & 63;
  int wave = __builtin_amdgcn_readfirstlane(tid >> 6);
  int wm = (wave >> 1) * 64, wn = (wave & 1) * 64;
  int m16 = lane & 15, qd = lane >> 4;

  const __hip_bfloat16* gA[4];
  const __hip_bfloat16* gB[4];
#pragma unroll
  for (int i2 = 0; i2 < 4; i2++) {
    int s = i2 * 256 + tid;
    int r = s >> 3;
    int q = (s & 7) ^ (r & 7);
    int rowA = mt * BM + r;
    int slot = rowA < n_e ? rowA : n_e - 1;   // clamp tail rows to valid slot
    int tok = idx[e * CAP + slot];
    gA[i2] = xb + (size_t)tok * DD + q * 8;
    gB[i2] = w1t + ((size_t)e * WW + nt * BN + r) * DD + q * 8;
  }
  short* ldsA[4];
  short* ldsB[4];
#pragma unroll
  for (int i2 = 0; i2 < 4; i2++) {
    ldsA[i2] = As + (i2 * 256 + wave * 64) * 8;
    ldsB[i2] = Bs + (i2 * 256 + wave * 64) * 8;
  }

  int aoff[4][2], boff[4][2];
#pragma unroll
  for (int mi = 0; mi < 4; mi++) {
    int r = wm + mi * 16 + m16;
#pragma unroll
    for (int h = 0; h < 2; h++)
      aoff[mi][h] = (r * 8 + ((qd + h * 4) ^ (r & 7))) * 8;
  }
#pragma unroll
  for (int ni = 0; ni < 4; ni++) {
    int r = wn + ni * 16 + m16;
#pragma unroll
    for (int h = 0; h < 2; h++)
      boff[ni][h] = (r * 8 + ((qd + h * 4) ^ (r & 7))) * 8;
  }

  f32x4 zero = {0.f, 0.f, 0.f, 0.f};
  f32x4 acc[4][4];
#pragma unroll
  for (int mi = 0; mi < 4; mi++)
#pragma unroll
    for (int ni = 0; ni < 4; ni++) acc[mi][ni] = zero;

  for (int k0 = 0; k0 < DD; k0 += BK) {
#pragma unroll
    for (int i2 = 0; i2 < 4; i2++) gload_lds16(gA[i2] + k0, ldsA[i2]);
#pragma unroll
    for (int i2 = 0; i2 < 4; i2++) gload_lds16(gB[i2] + k0, ldsB[i2]);
    __syncthreads();
#pragma unroll
    for (int h = 0; h < 2; h++) {
      bf16x8 af[4], bfr[4];
#pragma unroll
      for (int mi = 0; mi < 4; mi++) af[mi] = *(const bf16x8*)(As + aoff[mi][h]);
#pragma unroll
      for (int ni = 0; ni < 4; ni++) bfr[ni] = *(const bf16x8*)(Bs + boff[ni][h]);
#pragma unroll
      for (int mi = 0; mi < 4; mi++)
#pragma unroll
        for (int ni = 0; ni < 4; ni++)
          acc[mi][ni] = __builtin_amdgcn_mfma_f32_16x16x32_bf16(
              af[mi], bfr[ni], acc[mi][ni], 0, 0, 0);
    }
    __syncthreads();
  }

  // epilogue: relu^2 -> bf16 act[(e*CAP + slot)][col]
#pragma unroll
  for (int mi = 0; mi < 4; mi++) {
#pragma unroll
    for (int reg = 0; reg < 4; reg++) {
      int rowt = mt * BM + wm + mi * 16 + qd * 4 + reg;
      if (rowt < n_e) {
#pragma unroll
        for (int ni = 0; ni < 4; ni++) {
          float v = acc[mi][ni][reg];
          v = v > 0.f ? v * v : 0.f;
          int col = nt * BN + wn + ni * 16 + m16;
          act[((size_t)e * CAP + rowt) * WW + col] = __float2bfloat16(v);
        }
      }
    }
  }
}

// ---------------- grouped GEMM2 + fused combine ----------------
// y_row = act_row @ W2_e; out[tok] += wslot[slot] * y_row (fp32 atomics,
// exactly 2 addends per out element -> bitwise-deterministic).
__global__ __launch_bounds__(256, 3) void gemm2_kernel(
    const __hip_bfloat16* __restrict__ act, const __hip_bfloat16* __restrict__ w2t,
    const int* __restrict__ counts, const int* __restrict__ idx,
    const float* __restrict__ wslot, float* __restrict__ out)
{
  __shared__ __attribute__((aligned(16))) char smem[32768];
  short* As = (short*)smem;
  short* Bs = (short*)(smem + 16384);
  int bid = blockIdx.x;
  int e = bid & 7;
  int i = bid >> 3;
  int mt = i >> 3, nt = i & 7;
  int n_e = counts[e];
  if (mt * BM >= n_e) return;

  int tid = threadIdx.x;
  int lane = tid & 63;
  int wave = __builtin_amdgcn_readfirstlane(tid >> 6);
  int wm = (wave >> 1) * 64, wn = (wave & 1) * 64;
  int m16 = lane & 15, qd = lane >> 4;

  const __hip_bfloat16* gA[4];
  const __hip_bfloat16* gB[4];
#pragma unroll
  for (int i2 = 0; i2 < 4; i2++) {
    int s = i2 * 256 + tid;
    int r = s >> 3;
    int q = (s & 7) ^ (r & 7);
    // rows >= n_e: poison bytes, but row-isolated in MFMA -> discarded rows only
    gA[i2] = act + ((size_t)e * CAP + mt * BM + r) * WW + q * 8;
    gB[i2] = w2t + ((size_t)e * DD + nt * BN + r) * WW + q * 8;
  }
  short* ldsA[4];
  short* ldsB[4];
#pragma unroll
  for (int i2 = 0; i2 < 4; i2++) {
    ldsA[i2] = As + (i2 * 256 + wave * 64) * 8;
    ldsB[i2] = Bs + (i2 * 256 + wave * 64) * 8;
  }

  int aoff[4][2], boff[4][2];
#pragma unroll
  for (int mi = 0; mi < 4; mi++) {
    int r = wm + mi * 16 + m16;
#pragma unroll
    for (int h = 0; h < 2; h++)
      aoff[mi][h] = (r * 8 + ((qd + h * 4) ^ (r & 7))) * 8;
  }
#pragma unroll
  for (int ni = 0; ni < 4; ni++) {
    int r = wn + ni * 16 + m16;
#pragma unroll
    for (int h = 0; h < 2; h++)
      boff[ni][h] = (r * 8 + ((qd + h * 4) ^ (r & 7))) * 8;
  }

  f32x4 zero = {0.f, 0.f, 0.f, 0.f};
  f32x4 acc[4][4];
#pragma unroll
  for (int mi = 0; mi < 4; mi++)
#pragma unroll
    for (int ni = 0; ni < 4; ni++) acc[mi][ni] = zero;

  for (int k0 = 0; k0 < WW; k0 += BK) {
#pragma unroll
    for (int i2 = 0; i2 < 4; i2++) gload_lds16(gA[i2] + k0, ldsA[i2]);
#pragma unroll
    for (int i2 = 0; i2 < 4; i2++) gload_lds16(gB[i2] + k0, ldsB[i2]);
    __syncthreads();
#pragma unroll
    for (int h = 0; h < 2; h++) {
      bf16x8 af[4], bfr[4];
#pragma unroll
      for (int mi = 0; mi < 4; mi++) af[mi] = *(const bf16x8*)(As + aoff[mi][h]);
#pragma unroll
      for (int ni = 0; ni < 4; ni++) bfr[ni] = *(const bf16x8*)(Bs + boff[ni][h]);
#pragma unroll
      for (int mi = 0; mi < 4; mi++)
#pragma unroll
        for (int ni = 0; ni < 4; ni++)
          acc[mi][ni] = __builtin_amdgcn_mfma_f32_16x16x32_bf16(
              af[mi], bfr[ni], acc[mi][ni], 0, 0, 0);
    }
    __syncthreads();
  }

  // epilogue: fused combine -- out[tok][col] += w_row * v
#pragma unroll
  for (int mi = 0; mi < 4; mi++) {
#pragma unroll
    for (int reg = 0; reg < 4; reg++) {
      int slot = mt * BM + wm + mi * 16 + qd * 4 + reg;
      if (slot < n_e) {
        int tok = idx[e * CAP + slot];
        float wr = wslot[e * CAP + slot];
        float* orow = out + (size_t)tok * DD;
#pragma unroll
        for (int ni = 0; ni < 4; ni++) {
          int col = nt * BN + wn + ni * 16 + m16;
          unsafeAtomicAdd(orow + col, wr * acc[mi][ni][reg]);
        }
      }
    }
  }
}

extern "C" void kernel_launch(void* const* d_in, const int* in_sizes, int n_in,
                              void* d_out, int out_size, void* d_ws, size_t ws_size,
                              hipStream_t stream)
{
  const float* x  = (const float*)d_in[0];
  const float* rw = (const float*)d_in[1];
  const float* w1 = (const float*)d_in[2];
  const float* w2 = (const float*)d_in[3];
  float* out = (float*)d_out;

  char* ws = (char*)d_ws;
  __hip_bfloat16* xb  = (__hip_bfloat16*)ws;  ws += (size_t)T_TOKENS * DD * 2;
  __hip_bfloat16* w1t = (__hip_bfloat16*)ws;  ws += (size_t)EE * WW * DD * 2;
  __hip_bfloat16* w2t = (__hip_bfloat16*)ws;  ws += (size_t)EE * DD * WW * 2;
  __hip_bfloat16* act = (__hip_bfloat16*)ws;  ws += (size_t)EE * CAP * WW * 2;
  int*   counts = (int*)ws;                   ws += 256;
  int*   idx    = (int*)ws;                   ws += (size_t)EE * CAP * 4;
  int*   sel    = (int*)ws;                   ws += (size_t)T_TOKENS * 4;
  float* wslot  = (float*)ws;                 ws += (size_t)EE * CAP * 4;
  float* wpair  = (float*)ws;                 ws += (size_t)T_TOKENS * 8;

  // out accumulates via atomics -> must start zeroed (16MB, ~2.5us)
  hipMemsetAsync(out, 0, (size_t)T_TOKENS * DD * sizeof(float), stream);
  // k1: w1 transpose (512 blocks, 128x128 tiles) + router
  pre_kernel<<<TR1_BLOCKS + T_TOKENS / 4, 256, 0, stream>>>(
      w1, x, rw, w1t, xb, sel, wpair);
  // k2: deterministic contention-free list build (idx + wslot)
  build_lists<<<1, 1024, 0, stream>>>(sel, wpair, counts, idx, wslot);
  // k3: grouped GEMM1 + fused w2 transpose
  gemm1_kernel<<<GEMM_BLOCKS + TR2_BLOCKS, 256, 0, stream>>>(
      xb, w1t, counts, idx, act, w2, w2t);
  // k4: grouped GEMM2 + fused combine (atomics into out)
  gemm2_kernel<<<GEMM_BLOCKS, 256, 0, stream>>>(
      act, w2t, counts, idx, wslot, out);
}

// Round 8
// 197.753 us; speedup vs baseline: 1.0242x; 1.0242x over previous
//
#include <hip/hip_runtime.h>
#include <hip/hip_bf16.h>

// MoE MLP (top-2 of 8 experts), T=4096 tokens, D=1024, W=1024.
// R14: base = R10 (best passing, 188.8us). Mono-kernel abandoned for good
//      (R11 coop launch -> silent zeros; R13 manual barrier -> GPU hang).
//      R12's profile: gemm2 = 49.8us @ MfmaUtil 12.7%, Occ 19.6% (~345 TF)
//      with only ~512 working 128x128 blocks = 2/CU -> latency-bound GEMM.
//      ONE lever: BN 128 -> 64 (R6-proven gemm body): grid 1536, ~1090
//      working blocks = 4.3/CU, 24KB LDS, lb(256,4), acc[4][2]. Cross-block
//      overlap (m114) hides the 2-barrier K-step staging that 2 blocks/CU
//      could not.
// Retained: granule-XOR swizzle staging, expert=bid&7 XCD map, 128x128
//           transposes (w2t fused into gemm1 grid), ballot build_lists,
//           CAP=1536, gload_lds w16, separate combine kernel.

#define T_TOKENS 4096
#define DD 1024
#define EE 8
#define WW 1024
#define CAP 1536              // per-expert capacity (expected ~1024, sigma ~28)
#define BM 128
#define BN 64
#define BK 64
#define MT (CAP / BM)         // 12 m-tiles max per expert
#define NT (WW / BN)          // 16 n-tiles
#define GEMM_BLOCKS (EE * MT * NT)  // 1536
#define TR1_BLOCKS 512        // w1 transpose blocks (128x128 tiles, in pre)
#define TR2_BLOCKS 512        // w2 transpose blocks (in gemm1 grid)
#define TLD 132               // LDS transpose tile row stride (shorts), pad=4

typedef short bf16x8 __attribute__((ext_vector_type(8)));
typedef float f32x4 __attribute__((ext_vector_type(4)));

__device__ __forceinline__ void gload_lds16(const void* g, void* l) {
  __builtin_amdgcn_global_load_lds((__attribute__((address_space(1))) void*)(g),
                                   (__attribute__((address_space(3))) void*)(l),
                                   16, 0, 0);
}

__device__ __forceinline__ float bf2f(unsigned short u) {
  union { unsigned int i; float f; } v; v.i = (unsigned int)u << 16; return v.f;
}

__device__ __forceinline__ unsigned short f2bf_u(float f) {
  __hip_bfloat16 h = __float2bfloat16(f);
  union { __hip_bfloat16 h; unsigned short u; } c; c.h = h; return c.u;
}

// ---- 128x128 fp32->bf16 transpose tile through LDS (R10-proven) ----
// dst[(c0+c)*dst_ld + r0 + r] = bf16(src[(r0+r)*src_ld + c0 + c])
__device__ __forceinline__ void transpose_tile_128(
    const float* __restrict__ src, long src_ld, long r0, long c0,
    unsigned short* __restrict__ dst, long dst_ld, unsigned short* lds)
{
  int tid = threadIdx.x;
  int cq = tid & 31;            // covers 4 src cols
  int rb = tid >> 5;            // row base 0..7
#pragma unroll
  for (int i = 0; i < 16; i++) {
    int r = rb + i * 8;
    f32x4 v = *(const f32x4*)(src + (r0 + r) * src_ld + c0 + cq * 4);
#pragma unroll
    for (int j = 0; j < 4; j++)
      lds[(cq * 4 + j) * TLD + r] = f2bf_u(v[j]);
  }
  __syncthreads();
#pragma unroll
  for (int it = 0; it < 8; it++) {
    int slot = it * 256 + tid;
    int c = slot >> 4;          // dst row within tile
    int m = slot & 15;          // 8-elem chunk within row
    const unsigned short* p = lds + (size_t)c * TLD + m * 8;
    uint2 lo = *(const uint2*)(p);
    uint2 hi = *(const uint2*)(p + 4);
    uint4 o; o.x = lo.x; o.y = lo.y; o.z = hi.x; o.w = hi.y;
    *(uint4*)(dst + (c0 + c) * dst_ld + r0 + m * 8) = o;
  }
}

// ---------------- pre: w1 transpose (128x128 tiles) + router ----------------
// blocks [0,512): w1 transpose; [512,1536): router, 1 wave = 1 token.
__global__ __launch_bounds__(256) void pre_kernel(
    const float* __restrict__ w1, const float* __restrict__ x,
    const float* __restrict__ rw,
    __hip_bfloat16* __restrict__ w1t, __hip_bfloat16* __restrict__ xb,
    int* __restrict__ sel, float* __restrict__ wpair)
{
  __shared__ unsigned short lds_t[128 * TLD];   // 33792 B
  int b = blockIdx.x;
  if (b < TR1_BLOCKS) {
    // w1 [D=1024, E*W=8192] -> w1t [8192, 1024] bf16
    int bn = b >> 3;            // n-tile 0..63 (src col / dst row)
    int bd = b & 7;             // d-tile 0..7  (src row / dst col)
    transpose_tile_128(w1, EE * WW, (long)bd * 128, (long)bn * 128,
                       (unsigned short*)w1t, DD, lds_t);
  } else {
    // router: one wave per token, fp32 logits, top-2, no atomics
    int lane = threadIdx.x & 63;
    int wave = threadIdx.x >> 6;
    int t = (b - TR1_BLOCKS) * 4 + wave;
    const float* xrow = x + (size_t)t * DD;
    float acc[EE];
#pragma unroll
    for (int e = 0; e < EE; e++) acc[e] = 0.f;
#pragma unroll
    for (int i = 0; i < DD / 64; i++) {
      int d = lane + i * 64;
      float xv = xrow[d];
      xb[t * DD + d] = __float2bfloat16(xv);   // fused x -> bf16
#pragma unroll
      for (int e = 0; e < EE; e++) acc[e] += xv * rw[e * DD + d];
    }
#pragma unroll
    for (int e = 0; e < EE; e++) {
#pragma unroll
      for (int off = 32; off > 0; off >>= 1)
        acc[e] += __shfl_down(acc[e], off, 64);
    }
    if (lane == 0) {
      float p[EE];
#pragma unroll
      for (int e = 0; e < EE; e++) p[e] = 1.f / (1.f + expf(-acc[e]));
      // top-2, ties -> lowest index (matches jax.lax.top_k stable ordering)
      int e0 = 0; float b0 = p[0];
      for (int e = 1; e < EE; e++) if (p[e] > b0) { b0 = p[e]; e0 = e; }
      int e1 = -1; float b1 = -1.f;
      for (int e = 0; e < EE; e++) {
        if (e == e0) continue;
        if (p[e] > b1) { b1 = p[e]; e1 = e; }
      }
      float s = b0 + b1 + 1e-20f;
      sel[t] = e0 | (e1 << 8);
      wpair[2 * t]     = b0 / s;
      wpair[2 * t + 1] = b1 / s;
    }
  }
}

// ---------------- build per-expert token lists (1 block, wave-ballot agg) ----
__global__ __launch_bounds__(1024) void build_lists(
    const int* __restrict__ sel, int* __restrict__ counts,
    int* __restrict__ idx, int* __restrict__ tslot)
{
  __shared__ int lcnt[EE];
  int tid = threadIdx.x, lane = tid & 63;
  if (tid < EE) lcnt[tid] = 0;
  __syncthreads();
  unsigned long long lower = (1ull << lane) - 1;
#pragma unroll
  for (int j = 0; j < T_TOKENS / 1024; j++) {
    int t = j * 1024 + tid;
    int s = sel[t];
    int e0 = s & 0xff, e1 = (s >> 8) & 0xff;
    int slot0 = 0, slot1 = 0;
#pragma unroll
    for (int e = 0; e < EE; e++) {
      unsigned long long m0 = __ballot(e0 == e);
      unsigned long long m1 = __ballot(e1 == e);
      int c0 = __popcll(m0), c1 = __popcll(m1);
      int base = 0;
      if (lane == 0 && (c0 + c1) > 0) base = atomicAdd(&lcnt[e], c0 + c1);
      base = __shfl(base, 0, 64);
      if (e0 == e) slot0 = base + __popcll(m0 & lower);
      if (e1 == e) slot1 = base + c0 + __popcll(m1 & lower);
    }
    int p0 = e0 * CAP + slot0, p1 = e1 * CAP + slot1;
    idx[p0] = t; idx[p1] = t;
    tslot[2 * t] = p0; tslot[2 * t + 1] = p1;
  }
  __syncthreads();
  if (tid < EE) counts[tid] = lcnt[tid];
}

// ---------------- grouped GEMM1 (+ fused w2 transpose blocks) ----------------
// blocks [0,1536): act = relu(gather(xb) @ W1_e)^2, 128x64 tile, BK=64.
// blocks [1536, 1536+512): w2 [E*W,D] -> w2t[e] [D,W] bf16, 128x128 tiles.
// XCD map: expert = bid & 7.
__global__ __launch_bounds__(256, 4) void gemm1_kernel(
    const __hip_bfloat16* __restrict__ xb, const __hip_bfloat16* __restrict__ w1t,
    const int* __restrict__ counts, const int* __restrict__ idx,
    __hip_bfloat16* __restrict__ act,
    const float* __restrict__ w2, __hip_bfloat16* __restrict__ w2t)
{
  __shared__ __attribute__((aligned(16))) char smem[128 * TLD * 2]; // 33792B
  int bid = blockIdx.x;
  if (bid >= GEMM_BLOCKS) {
    // ---- w2 transpose: expert slice [W,D] -> w2t[e] [D,W] ----
    int z = bid - GEMM_BLOCKS;      // 0..511
    int e = z >> 6;                 // 64 tiles per expert
    int t2 = z & 63;
    transpose_tile_128(w2 + (long)e * WW * DD, DD,
                       (long)(t2 >> 3) * 128, (long)(t2 & 7) * 128,
                       (unsigned short*)(w2t + (long)e * DD * WW), WW,
                       (unsigned short*)smem);
    return;
  }
  short* As = (short*)smem;               // 16 KB
  short* Bs = (short*)(smem + 16384);     // 8 KB
  int e = bid & 7;
  int i = bid >> 3;
  int mt = i >> 4, nt = i & 15;
  int n_e = counts[e];
  if (mt * BM >= n_e) return;

  int tid = threadIdx.x;
  int lane = tid & 63;
  int wave = __builtin_amdgcn_readfirstlane(tid >> 6);
  int wm = (wave >> 1) * 64, wn = (wave & 1) * 32;
  int m16 = lane & 15, qd = lane >> 4;

  // staging: granule = 16B (8 bf16); 8 granule-cols/row; slot s -> row s>>3,
  // swizzled col (s&7)^(r&7). A: 4 issues/thread, B: 2 (R6-proven).
  const __hip_bfloat16* gA[4];
  const __hip_bfloat16* gB[2];
#pragma unroll
  for (int i2 = 0; i2 < 4; i2++) {
    int s = i2 * 256 + tid;
    int r = s >> 3;
    int q = (s & 7) ^ (r & 7);
    int rowA = mt * BM + r;
    int slot = rowA < n_e ? rowA : n_e - 1;   // clamp tail rows to valid slot
    int tok = idx[e * CAP + slot];
    gA[i2] = xb + (size_t)tok * DD + q * 8;
  }
#pragma unroll
  for (int i2 = 0; i2 < 2; i2++) {
    int s = i2 * 256 + tid;
    int r = s >> 3;
    int q = (s & 7) ^ (r & 7);
    gB[i2] = w1t + ((size_t)e * WW + nt * BN + r) * DD + q * 8;
  }
  short* ldsA[4];
  short* ldsB[2];
#pragma unroll
  for (int i2 = 0; i2 < 4; i2++) ldsA[i2] = As + (i2 * 256 + wave * 64) * 8;
#pragma unroll
  for (int i2 = 0; i2 < 2; i2++) ldsB[i2] = Bs + (i2 * 256 + wave * 64) * 8;

  int aoff[4][2], boff[2][2];
#pragma unroll
  for (int mi = 0; mi < 4; mi++) {
    int r = wm + mi * 16 + m16;
#pragma unroll
    for (int h = 0; h < 2; h++)
      aoff[mi][h] = (r * 8 + ((qd + h * 4) ^ (r & 7))) * 8;
  }
#pragma unroll
  for (int j = 0; j < 2; j++) {
    int r = wn + j * 16 + m16;
#pragma unroll
    for (int h = 0; h < 2; h++)
      boff[j][h] = (r * 8 + ((qd + h * 4) ^ (r & 7))) * 8;
  }

  f32x4 zero = {0.f, 0.f, 0.f, 0.f};
  f32x4 acc[4][2];
#pragma unroll
  for (int mi = 0; mi < 4; mi++)
#pragma unroll
    for (int ni = 0; ni < 2; ni++) acc[mi][ni] = zero;

  for (int k0 = 0; k0 < DD; k0 += BK) {
    gload_lds16(gA[0] + k0, ldsA[0]);
    gload_lds16(gA[1] + k0, ldsA[1]);
    gload_lds16(gA[2] + k0, ldsA[2]);
    gload_lds16(gA[3] + k0, ldsA[3]);
    gload_lds16(gB[0] + k0, ldsB[0]);
    gload_lds16(gB[1] + k0, ldsB[1]);
    __syncthreads();
#pragma unroll
    for (int h = 0; h < 2; h++) {
      bf16x8 af[4], bfr[2];
#pragma unroll
      for (int mi = 0; mi < 4; mi++) af[mi] = *(const bf16x8*)(As + aoff[mi][h]);
#pragma unroll
      for (int j = 0; j < 2; j++) bfr[j] = *(const bf16x8*)(Bs + boff[j][h]);
#pragma unroll
      for (int mi = 0; mi < 4; mi++)
#pragma unroll
        for (int ni = 0; ni < 2; ni++)
          acc[mi][ni] = __builtin_amdgcn_mfma_f32_16x16x32_bf16(
              af[mi], bfr[ni], acc[mi][ni], 0, 0, 0);
    }
    __syncthreads();
  }

  // epilogue: relu^2 -> bf16 act[(e*CAP + slot)][col]
#pragma unroll
  for (int mi = 0; mi < 4; mi++) {
#pragma unroll
    for (int reg = 0; reg < 4; reg++) {
      int rowt = mt * BM + wm + mi * 16 + qd * 4 + reg;
      if (rowt < n_e) {
#pragma unroll
        for (int ni = 0; ni < 2; ni++) {
          float v = acc[mi][ni][reg];
          v = v > 0.f ? v * v : 0.f;
          int col = nt * BN + wn + ni * 16 + m16;
          act[((size_t)e * CAP + rowt) * WW + col] = __float2bfloat16(v);
        }
      }
    }
  }
}

// ---------------- grouped GEMM2: y = act @ W2_e (raw bf16 y) ----------------
__global__ __launch_bounds__(256, 4) void gemm2_kernel(
    const __hip_bfloat16* __restrict__ act, const __hip_bfloat16* __restrict__ w2t,
    const int* __restrict__ counts, __hip_bfloat16* __restrict__ y)
{
  __shared__ __attribute__((aligned(16))) char smem[24576];
  short* As = (short*)smem;
  short* Bs = (short*)(smem + 16384);
  int bid = blockIdx.x;
  int e = bid & 7;
  int i = bid >> 3;
  int mt = i >> 4, nt = i & 15;
  int n_e = counts[e];
  if (mt * BM >= n_e) return;

  int tid = threadIdx.x;
  int lane = tid & 63;
  int wave = __builtin_amdgcn_readfirstlane(tid >> 6);
  int wm = (wave >> 1) * 64, wn = (wave & 1) * 32;
  int m16 = lane & 15, qd = lane >> 4;

  const __hip_bfloat16* gA[4];
  const __hip_bfloat16* gB[2];
#pragma unroll
  for (int i2 = 0; i2 < 4; i2++) {
    int s = i2 * 256 + tid;
    int r = s >> 3;
    int q = (s & 7) ^ (r & 7);
    // rows >= n_e: poison bytes, but row-isolated in MFMA -> discarded rows only
    gA[i2] = act + ((size_t)e * CAP + mt * BM + r) * WW + q * 8;
  }
#pragma unroll
  for (int i2 = 0; i2 < 2; i2++) {
    int s = i2 * 256 + tid;
    int r = s >> 3;
    int q = (s & 7) ^ (r & 7);
    gB[i2] = w2t + ((size_t)e * DD + nt * BN + r) * WW + q * 8;
  }
  short* ldsA[4];
  short* ldsB[2];
#pragma unroll
  for (int i2 = 0; i2 < 4; i2++) ldsA[i2] = As + (i2 * 256 + wave * 64) * 8;
#pragma unroll
  for (int i2 = 0; i2 < 2; i2++) ldsB[i2] = Bs + (i2 * 256 + wave * 64) * 8;

  int aoff[4][2], boff[2][2];
#pragma unroll
  for (int mi = 0; mi < 4; mi++) {
    int r = wm + mi * 16 + m16;
#pragma unroll
    for (int h = 0; h < 2; h++)
      aoff[mi][h] = (r * 8 + ((qd + h * 4) ^ (r & 7))) * 8;
  }
#pragma unroll
  for (int j = 0; j < 2; j++) {
    int r = wn + j * 16 + m16;
#pragma unroll
    for (int h = 0; h < 2; h++)
      boff[j][h] = (r * 8 + ((qd + h * 4) ^ (r & 7))) * 8;
  }

  f32x4 zero = {0.f, 0.f, 0.f, 0.f};
  f32x4 acc[4][2];
#pragma unroll
  for (int mi = 0; mi < 4; mi++)
#pragma unroll
    for (int ni = 0; ni < 2; ni++) acc[mi][ni] = zero;

  for (int k0 = 0; k0 < WW; k0 += BK) {
    gload_lds16(gA[0] + k0, ldsA[0]);
    gload_lds16(gA[1] + k0, ldsA[1]);
    gload_lds16(gA[2] + k0, ldsA[2]);
    gload_lds16(gA[3] + k0, ldsA[3]);
    gload_lds16(gB[0] + k0, ldsB[0]);
    gload_lds16(gB[1] + k0, ldsB[1]);
    __syncthreads();
#pragma unroll
    for (int h = 0; h < 2; h++) {
      bf16x8 af[4], bfr[2];
#pragma unroll
      for (int mi = 0; mi < 4; mi++) af[mi] = *(const bf16x8*)(As + aoff[mi][h]);
#pragma unroll
      for (int j = 0; j < 2; j++) bfr[j] = *(const bf16x8*)(Bs + boff[j][h]);
#pragma unroll
      for (int mi = 0; mi < 4; mi++)
#pragma unroll
        for (int ni = 0; ni < 2; ni++)
          acc[mi][ni] = __builtin_amdgcn_mfma_f32_16x16x32_bf16(
              af[mi], bfr[ni], acc[mi][ni], 0, 0, 0);
    }
    __syncthreads();
  }

  // epilogue: raw y (routing weights applied in combine)
#pragma unroll
  for (int mi = 0; mi < 4; mi++) {
#pragma unroll
    for (int reg = 0; reg < 4; reg++) {
      int slot = mt * BM + wm + mi * 16 + qd * 4 + reg;
      if (slot < n_e) {
#pragma unroll
        for (int ni = 0; ni < 2; ni++) {
          int col = nt * BN + wn + ni * 16 + m16;
          y[((size_t)e * CAP + slot) * DD + col] = __float2bfloat16(acc[mi][ni][reg]);
        }
      }
    }
  }
}

// ---------------- combine: out[t] = w0*y[slot0] + w1*y[slot1] ----------------
__global__ __launch_bounds__(256) void combine_kernel(
    const __hip_bfloat16* __restrict__ y, const int* __restrict__ tslot,
    const float* __restrict__ wpair, float* __restrict__ out)
{
  int t = blockIdx.x;
  int c = threadIdx.x * 4;
  int s0 = tslot[2 * t], s1 = tslot[2 * t + 1];
  float w0 = wpair[2 * t], w1 = wpair[2 * t + 1];
  const unsigned short* yu = (const unsigned short*)y;
  ushort4 a = *(const ushort4*)(yu + (size_t)s0 * DD + c);
  ushort4 bq = *(const ushort4*)(yu + (size_t)s1 * DD + c);
  f32x4 o;
  o[0] = w0 * bf2f(a.x) + w1 * bf2f(bq.x);
  o[1] = w0 * bf2f(a.y) + w1 * bf2f(bq.y);
  o[2] = w0 * bf2f(a.z) + w1 * bf2f(bq.z);
  o[3] = w0 * bf2f(a.w) + w1 * bf2f(bq.w);
  *(f32x4*)(out + (size_t)t * DD + c) = o;
}

extern "C" void kernel_launch(void* const* d_in, const int* in_sizes, int n_in,
                              void* d_out, int out_size, void* d_ws, size_t ws_size,
                              hipStream_t stream)
{
  const float* x  = (const float*)d_in[0];
  const float* rw = (const float*)d_in[1];
  const float* w1 = (const float*)d_in[2];
  const float* w2 = (const float*)d_in[3];
  float* out = (float*)d_out;

  char* ws = (char*)d_ws;
  __hip_bfloat16* xb  = (__hip_bfloat16*)ws;  ws += (size_t)T_TOKENS * DD * 2;
  __hip_bfloat16* w1t = (__hip_bfloat16*)ws;  ws += (size_t)EE * WW * DD * 2;
  __hip_bfloat16* w2t = (__hip_bfloat16*)ws;  ws += (size_t)EE * DD * WW * 2;
  __hip_bfloat16* act = (__hip_bfloat16*)ws;  ws += (size_t)EE * CAP * WW * 2;
  __hip_bfloat16* y   = (__hip_bfloat16*)ws;  ws += (size_t)EE * CAP * DD * 2;
  int*   counts = (int*)ws;                   ws += 256;
  int*   idx    = (int*)ws;                   ws += (size_t)EE * CAP * 4;
  int*   sel    = (int*)ws;                   ws += (size_t)T_TOKENS * 4;
  int*   tslot  = (int*)ws;                   ws += (size_t)T_TOKENS * 8;
  float* wpair  = (float*)ws;                 ws += (size_t)T_TOKENS * 8;

  // k1: w1 transpose (512 blocks, 128x128 tiles) + router
  pre_kernel<<<TR1_BLOCKS + T_TOKENS / 4, 256, 0, stream>>>(
      w1, x, rw, w1t, xb, sel, wpair);
  // k2: deterministic contention-free list build
  build_lists<<<1, 1024, 0, stream>>>(sel, counts, idx, tslot);
  // k3: grouped GEMM1 (128x64 tiles, 1536 blocks) + fused w2 transpose
  gemm1_kernel<<<GEMM_BLOCKS + TR2_BLOCKS, 256, 0, stream>>>(
      xb, w1t, counts, idx, act, w2, w2t);
  // k4: grouped GEMM2 (128x64 tiles)
  gemm2_kernel<<<GEMM_BLOCKS, 256, 0, stream>>>(act, w2t, counts, y);
  // k5: weighted combine
  combine_kernel<<<T_TOKENS, 256, 0, stream>>>(y, tslot, wpair, out);
}

// Round 9
// 190.103 us; speedup vs baseline: 1.0654x; 1.0402x over previous
//
#include <hip/hip_runtime.h>
#include <hip/hip_bf16.h>

// MoE MLP (top-2 of 8 experts), T=4096 tokens, D=1024, W=1024.
// R15: base = R10 (best passing, 188.8us; 128x128 GEMM confirmed best by
//      R6/R8/R14). R14's profile: GEMM time invariant to occupancy (2 vs 4
//      blocks/CU) => K-loop exposes HBM-class latency; FETCH 37MB > 24MB
//      ideal => B-panels not L2-local. Root cause: transpose producer blocks
//      are round-robin across XCDs while consumer (expert e) is pinned to
//      XCD e. TWO index-permutation changes (zero numerics risk):
//      (1) XCD-aligned transposes: w1t/w2t tile for expert e handled by a
//          block with bid%8 == e -> producer L2 = consumer L2.
//      (2) w2 transposes at the FRONT of gemm1's grid (no cold tail; w2t
//          warm in XCD-e L2 when gemm2 starts).
// Retained: 128x128 GEMM tile BK=64 granule-XOR swizzle, ballot build_lists,
//           128x128 transposes, CAP=1536, gload_lds w16, separate combine.

#define T_TOKENS 4096
#define DD 1024
#define EE 8
#define WW 1024
#define CAP 1536              // per-expert capacity (expected ~1024, sigma ~28)
#define BM 128
#define BN 128
#define BK 64
#define MT (CAP / BM)         // 12 m-tiles max per expert
#define NT (WW / BN)          // 8 n-tiles
#define GEMM_BLOCKS (EE * MT * NT)  // 768
#define TR1_BLOCKS 512        // w1 transpose blocks (128x128 tiles, in pre)
#define TR2_BLOCKS 512        // w2 transpose blocks (FRONT of gemm1 grid)
#define TLD 132               // LDS transpose tile row stride (shorts), pad=4

typedef short bf16x8 __attribute__((ext_vector_type(8)));
typedef float f32x4 __attribute__((ext_vector_type(4)));

__device__ __forceinline__ void gload_lds16(const void* g, void* l) {
  __builtin_amdgcn_global_load_lds((__attribute__((address_space(1))) void*)(g),
                                   (__attribute__((address_space(3))) void*)(l),
                                   16, 0, 0);
}

__device__ __forceinline__ float bf2f(unsigned short u) {
  union { unsigned int i; float f; } v; v.i = (unsigned int)u << 16; return v.f;
}

__device__ __forceinline__ unsigned short f2bf_u(float f) {
  __hip_bfloat16 h = __float2bfloat16(f);
  union { __hip_bfloat16 h; unsigned short u; } c; c.h = h; return c.u;
}

// ---- 128x128 fp32->bf16 transpose tile through LDS (R10-proven) ----
// dst[(c0+c)*dst_ld + r0 + r] = bf16(src[(r0+r)*src_ld + c0 + c])
__device__ __forceinline__ void transpose_tile_128(
    const float* __restrict__ src, long src_ld, long r0, long c0,
    unsigned short* __restrict__ dst, long dst_ld, unsigned short* lds)
{
  int tid = threadIdx.x;
  int cq = tid & 31;            // covers 4 src cols
  int rb = tid >> 5;            // row base 0..7
#pragma unroll
  for (int i = 0; i < 16; i++) {
    int r = rb + i * 8;
    f32x4 v = *(const f32x4*)(src + (r0 + r) * src_ld + c0 + cq * 4);
#pragma unroll
    for (int j = 0; j < 4; j++)
      lds[(cq * 4 + j) * TLD + r] = f2bf_u(v[j]);
  }
  __syncthreads();
#pragma unroll
  for (int it = 0; it < 8; it++) {
    int slot = it * 256 + tid;
    int c = slot >> 4;          // dst row within tile
    int m = slot & 15;          // 8-elem chunk within row
    const unsigned short* p = lds + (size_t)c * TLD + m * 8;
    uint2 lo = *(const uint2*)(p);
    uint2 hi = *(const uint2*)(p + 4);
    uint4 o; o.x = lo.x; o.y = lo.y; o.z = hi.x; o.w = hi.y;
    *(uint4*)(dst + (c0 + c) * dst_ld + r0 + m * 8) = o;
  }
}

// ---------------- pre: w1 transpose (XCD-aligned) + router ----------------
// blocks [0,512): w1 transpose, expert slab = b&7 (matches gemm1's XCD map);
// blocks [512,1536): router, 1 wave = 1 token.
__global__ __launch_bounds__(256) void pre_kernel(
    const float* __restrict__ w1, const float* __restrict__ x,
    const float* __restrict__ rw,
    __hip_bfloat16* __restrict__ w1t, __hip_bfloat16* __restrict__ xb,
    int* __restrict__ sel, float* __restrict__ wpair)
{
  __shared__ unsigned short lds_t[128 * TLD];   // 33792 B
  int b = blockIdx.x;
  if (b < TR1_BLOCKS) {
    // w1 [D=1024, E*W=8192] -> w1t [8192, 1024] bf16.
    // XCD-aligned: expert e = b&7 -> this block runs on XCD e (round-robin),
    // the same XCD where gemm1 will read slab e. 64 tiles per expert.
    int e = b & 7;
    int t = b >> 3;             // 0..63
    int bn = e * 8 + (t >> 3);  // dst row tile (expert slab rows e*1024..)
    int bd = t & 7;             // dst col tile
    transpose_tile_128(w1, EE * WW, (long)bd * 128, (long)bn * 128,
                       (unsigned short*)w1t, DD, lds_t);
  } else {
    // router: one wave per token, fp32 logits, top-2, no atomics
    int lane = threadIdx.x & 63;
    int wave = threadIdx.x >> 6;
    int t = (b - TR1_BLOCKS) * 4 + wave;
    const float* xrow = x + (size_t)t * DD;
    float acc[EE];
#pragma unroll
    for (int e = 0; e < EE; e++) acc[e] = 0.f;
#pragma unroll
    for (int i = 0; i < DD / 64; i++) {
      int d = lane + i * 64;
      float xv = xrow[d];
      xb[t * DD + d] = __float2bfloat16(xv);   // fused x -> bf16
#pragma unroll
      for (int e = 0; e < EE; e++) acc[e] += xv * rw[e * DD + d];
    }
#pragma unroll
    for (int e = 0; e < EE; e++) {
#pragma unroll
      for (int off = 32; off > 0; off >>= 1)
        acc[e] += __shfl_down(acc[e], off, 64);
    }
    if (lane == 0) {
      float p[EE];
#pragma unroll
      for (int e = 0; e < EE; e++) p[e] = 1.f / (1.f + expf(-acc[e]));
      // top-2, ties -> lowest index (matches jax.lax.top_k stable ordering)
      int e0 = 0; float b0 = p[0];
      for (int e = 1; e < EE; e++) if (p[e] > b0) { b0 = p[e]; e0 = e; }
      int e1 = -1; float b1 = -1.f;
      for (int e = 0; e < EE; e++) {
        if (e == e0) continue;
        if (p[e] > b1) { b1 = p[e]; e1 = e; }
      }
      float s = b0 + b1 + 1e-20f;
      sel[t] = e0 | (e1 << 8);
      wpair[2 * t]     = b0 / s;
      wpair[2 * t + 1] = b1 / s;
    }
  }
}

// ---------------- build per-expert token lists (1 block, wave-ballot agg) ----
__global__ __launch_bounds__(1024) void build_lists(
    const int* __restrict__ sel, int* __restrict__ counts,
    int* __restrict__ idx, int* __restrict__ tslot)
{
  __shared__ int lcnt[EE];
  int tid = threadIdx.x, lane = tid & 63;
  if (tid < EE) lcnt[tid] = 0;
  __syncthreads();
  unsigned long long lower = (1ull << lane) - 1;
#pragma unroll
  for (int j = 0; j < T_TOKENS / 1024; j++) {
    int t = j * 1024 + tid;
    int s = sel[t];
    int e0 = s & 0xff, e1 = (s >> 8) & 0xff;
    int slot0 = 0, slot1 = 0;
#pragma unroll
    for (int e = 0; e < EE; e++) {
      unsigned long long m0 = __ballot(e0 == e);
      unsigned long long m1 = __ballot(e1 == e);
      int c0 = __popcll(m0), c1 = __popcll(m1);
      int base = 0;
      if (lane == 0 && (c0 + c1) > 0) base = atomicAdd(&lcnt[e], c0 + c1);
      base = __shfl(base, 0, 64);
      if (e0 == e) slot0 = base + __popcll(m0 & lower);
      if (e1 == e) slot1 = base + c0 + __popcll(m1 & lower);
    }
    int p0 = e0 * CAP + slot0, p1 = e1 * CAP + slot1;
    idx[p0] = t; idx[p1] = t;
    tslot[2 * t] = p0; tslot[2 * t + 1] = p1;
  }
  __syncthreads();
  if (tid < EE) counts[tid] = lcnt[tid];
}

// ---------------- grouped GEMM1 (w2 transposes at FRONT, XCD-aligned) -------
// blocks [0,512): w2 [E*W,D] -> w2t[e=bid&7] [D,W] bf16 (producer XCD = e =
//   consumer XCD for gemm2). blocks [512, 512+768): GEMM, expert = bid&7
//   (512%8==0 preserves the map), act = relu(gather(xb) @ W1_e)^2.
__global__ __launch_bounds__(256, 3) void gemm1_kernel(
    const __hip_bfloat16* __restrict__ xb, const __hip_bfloat16* __restrict__ w1t,
    const int* __restrict__ counts, const int* __restrict__ idx,
    __hip_bfloat16* __restrict__ act,
    const float* __restrict__ w2, __hip_bfloat16* __restrict__ w2t)
{
  __shared__ __attribute__((aligned(16))) char smem[128 * TLD * 2]; // 33792B
  int bid = blockIdx.x;
  if (bid < TR2_BLOCKS) {
    // ---- w2 transpose: expert slice [W,D] -> w2t[e] [D,W], e = bid&7 ----
    int e = bid & 7;
    int t2 = bid >> 3;              // 0..63
    transpose_tile_128(w2 + (long)e * WW * DD, DD,
                       (long)(t2 >> 3) * 128, (long)(t2 & 7) * 128,
                       (unsigned short*)(w2t + (long)e * DD * WW), WW,
                       (unsigned short*)smem);
    return;
  }
  short* As = (short*)smem;
  short* Bs = (short*)(smem + 16384);
  int g = bid - TR2_BLOCKS;
  int e = g & 7;
  int i = g >> 3;
  int mt = i >> 3, nt = i & 7;
  int n_e = counts[e];
  if (mt * BM >= n_e) return;

  int tid = threadIdx.x;
  int lane = tid & 63;
  int wave = __builtin_amdgcn_readfirstlane(tid >> 6);
  int wm = (wave >> 1) * 64, wn = (wave & 1) * 64;
  int m16 = lane & 15, qd = lane >> 4;

  // staging: granule = 16B (8 bf16); 8 granule-cols/row; slot s -> row s>>3,
  // swizzled col (s&7)^(r&7); LDS dest linear (gload_lds is base+lane*16).
  const __hip_bfloat16* gA[4];
  const __hip_bfloat16* gB[4];
#pragma unroll
  for (int i2 = 0; i2 < 4; i2++) {
    int s = i2 * 256 + tid;
    int r = s >> 3;
    int q = (s & 7) ^ (r & 7);
    int rowA = mt * BM + r;
    int slot = rowA < n_e ? rowA : n_e - 1;   // clamp tail rows to valid slot
    int tok = idx[e * CAP + slot];
    gA[i2] = xb + (size_t)tok * DD + q * 8;
    gB[i2] = w1t + ((size_t)e * WW + nt * BN + r) * DD + q * 8;
  }
  short* ldsA[4];
  short* ldsB[4];
#pragma unroll
  for (int i2 = 0; i2 < 4; i2++) {
    ldsA[i2] = As + (i2 * 256 + wave * 64) * 8;
    ldsB[i2] = Bs + (i2 * 256 + wave * 64) * 8;
  }

  int aoff[4][2], boff[4][2];
#pragma unroll
  for (int mi = 0; mi < 4; mi++) {
    int r = wm + mi * 16 + m16;
#pragma unroll
    for (int h = 0; h < 2; h++)
      aoff[mi][h] = (r * 8 + ((qd + h * 4) ^ (r & 7))) * 8;
  }
#pragma unroll
  for (int ni = 0; ni < 4; ni++) {
    int r = wn + ni * 16 + m16;
#pragma unroll
    for (int h = 0; h < 2; h++)
      boff[ni][h] = (r * 8 + ((qd + h * 4) ^ (r & 7))) * 8;
  }

  f32x4 zero = {0.f, 0.f, 0.f, 0.f};
  f32x4 acc[4][4];
#pragma unroll
  for (int mi = 0; mi < 4; mi++)
#pragma unroll
    for (int ni = 0; ni < 4; ni++) acc[mi][ni] = zero;

  for (int k0 = 0; k0 < DD; k0 += BK) {
#pragma unroll
    for (int i2 = 0; i2 < 4; i2++) gload_lds16(gA[i2] + k0, ldsA[i2]);
#pragma unroll
    for (int i2 = 0; i2 < 4; i2++) gload_lds16(gB[i2] + k0, ldsB[i2]);
    __syncthreads();
#pragma unroll
    for (int h = 0; h < 2; h++) {
      bf16x8 af[4], bfr[4];
#pragma unroll
      for (int mi = 0; mi < 4; mi++) af[mi] = *(const bf16x8*)(As + aoff[mi][h]);
#pragma unroll
      for (int ni = 0; ni < 4; ni++) bfr[ni] = *(const bf16x8*)(Bs + boff[ni][h]);
#pragma unroll
      for (int mi = 0; mi < 4; mi++)
#pragma unroll
        for (int ni = 0; ni < 4; ni++)
          acc[mi][ni] = __builtin_amdgcn_mfma_f32_16x16x32_bf16(
              af[mi], bfr[ni], acc[mi][ni], 0, 0, 0);
    }
    __syncthreads();
  }

  // epilogue: relu^2 -> bf16 act[(e*CAP + slot)][col]
#pragma unroll
  for (int mi = 0; mi < 4; mi++) {
#pragma unroll
    for (int reg = 0; reg < 4; reg++) {
      int rowt = mt * BM + wm + mi * 16 + qd * 4 + reg;
      if (rowt < n_e) {
#pragma unroll
        for (int ni = 0; ni < 4; ni++) {
          float v = acc[mi][ni][reg];
          v = v > 0.f ? v * v : 0.f;
          int col = nt * BN + wn + ni * 16 + m16;
          act[((size_t)e * CAP + rowt) * WW + col] = __float2bfloat16(v);
        }
      }
    }
  }
}

// ---------------- grouped GEMM2: y = act @ W2_e (raw bf16 y) ----------------
__global__ __launch_bounds__(256, 3) void gemm2_kernel(
    const __hip_bfloat16* __restrict__ act, const __hip_bfloat16* __restrict__ w2t,
    const int* __restrict__ counts, __hip_bfloat16* __restrict__ y)
{
  __shared__ __attribute__((aligned(16))) char smem[32768];
  short* As = (short*)smem;
  short* Bs = (short*)(smem + 16384);
  int bid = blockIdx.x;
  int e = bid & 7;
  int i = bid >> 3;
  int mt = i >> 3, nt = i & 7;
  int n_e = counts[e];
  if (mt * BM >= n_e) return;

  int tid = threadIdx.x;
  int lane = tid & 63;
  int wave = __builtin_amdgcn_readfirstlane(tid >> 6);
  int wm = (wave >> 1) * 64, wn = (wave & 1) * 64;
  int m16 = lane & 15, qd = lane >> 4;

  const __hip_bfloat16* gA[4];
  const __hip_bfloat16* gB[4];
#pragma unroll
  for (int i2 = 0; i2 < 4; i2++) {
    int s = i2 * 256 + tid;
    int r = s >> 3;
    int q = (s & 7) ^ (r & 7);
    // rows >= n_e: poison bytes, but row-isolated in MFMA -> discarded rows only
    gA[i2] = act + ((size_t)e * CAP + mt * BM + r) * WW + q * 8;
    gB[i2] = w2t + ((size_t)e * DD + nt * BN + r) * WW + q * 8;
  }
  short* ldsA[4];
  short* ldsB[4];
#pragma unroll
  for (int i2 = 0; i2 < 4; i2++) {
    ldsA[i2] = As + (i2 * 256 + wave * 64) * 8;
    ldsB[i2] = Bs + (i2 * 256 + wave * 64) * 8;
  }

  int aoff[4][2], boff[4][2];
#pragma unroll
  for (int mi = 0; mi < 4; mi++) {
    int r = wm + mi * 16 + m16;
#pragma unroll
    for (int h = 0; h < 2; h++)
      aoff[mi][h] = (r * 8 + ((qd + h * 4) ^ (r & 7))) * 8;
  }
#pragma unroll
  for (int ni = 0; ni < 4; ni++) {
    int r = wn + ni * 16 + m16;
#pragma unroll
    for (int h = 0; h < 2; h++)
      boff[ni][h] = (r * 8 + ((qd + h * 4) ^ (r & 7))) * 8;
  }

  f32x4 zero = {0.f, 0.f, 0.f, 0.f};
  f32x4 acc[4][4];
#pragma unroll
  for (int mi = 0; mi < 4; mi++)
#pragma unroll
    for (int ni = 0; ni < 4; ni++) acc[mi][ni] = zero;

  for (int k0 = 0; k0 < WW; k0 += BK) {
#pragma unroll
    for (int i2 = 0; i2 < 4; i2++) gload_lds16(gA[i2] + k0, ldsA[i2]);
#pragma unroll
    for (int i2 = 0; i2 < 4; i2++) gload_lds16(gB[i2] + k0, ldsB[i2]);
    __syncthreads();
#pragma unroll
    for (int h = 0; h < 2; h++) {
      bf16x8 af[4], bfr[4];
#pragma unroll
      for (int mi = 0; mi < 4; mi++) af[mi] = *(const bf16x8*)(As + aoff[mi][h]);
#pragma unroll
      for (int ni = 0; ni < 4; ni++) bfr[ni] = *(const bf16x8*)(Bs + boff[ni][h]);
#pragma unroll
      for (int mi = 0; mi < 4; mi++)
#pragma unroll
        for (int ni = 0; ni < 4; ni++)
          acc[mi][ni] = __builtin_amdgcn_mfma_f32_16x16x32_bf16(
              af[mi], bfr[ni], acc[mi][ni], 0, 0, 0);
    }
    __syncthreads();
  }

  // epilogue: raw y (routing weights applied in combine)
#pragma unroll
  for (int mi = 0; mi < 4; mi++) {
#pragma unroll
    for (int reg = 0; reg < 4; reg++) {
      int slot = mt * BM + wm + mi * 16 + qd * 4 + reg;
      if (slot < n_e) {
#pragma unroll
        for (int ni = 0; ni < 4; ni++) {
          int col = nt * BN + wn + ni * 16 + m16;
          y[((size_t)e * CAP + slot) * DD + col] = __float2bfloat16(acc[mi][ni][reg]);
        }
      }
    }
  }
}

// ---------------- combine: out[t] = w0*y[slot0] + w1*y[slot1] ----------------
__global__ __launch_bounds__(256) void combine_kernel(
    const __hip_bfloat16* __restrict__ y, const int* __restrict__ tslot,
    const float* __restrict__ wpair, float* __restrict__ out)
{
  int t = blockIdx.x;
  int c = threadIdx.x * 4;
  int s0 = tslot[2 * t], s1 = tslot[2 * t + 1];
  float w0 = wpair[2 * t], w1 = wpair[2 * t + 1];
  const unsigned short* yu = (const unsigned short*)y;
  ushort4 a = *(const ushort4*)(yu + (size_t)s0 * DD + c);
  ushort4 bq = *(const ushort4*)(yu + (size_t)s1 * DD + c);
  f32x4 o;
  o[0] = w0 * bf2f(a.x) + w1 * bf2f(bq.x);
  o[1] = w0 * bf2f(a.y) + w1 * bf2f(bq.y);
  o[2] = w0 * bf2f(a.z) + w1 * bf2f(bq.z);
  o[3] = w0 * bf2f(a.w) + w1 * bf2f(bq.w);
  *(f32x4*)(out + (size_t)t * DD + c) = o;
}

extern "C" void kernel_launch(void* const* d_in, const int* in_sizes, int n_in,
                              void* d_out, int out_size, void* d_ws, size_t ws_size,
                              hipStream_t stream)
{
  const float* x  = (const float*)d_in[0];
  const float* rw = (const float*)d_in[1];
  const float* w1 = (const float*)d_in[2];
  const float* w2 = (const float*)d_in[3];
  float* out = (float*)d_out;

  char* ws = (char*)d_ws;
  __hip_bfloat16* xb  = (__hip_bfloat16*)ws;  ws += (size_t)T_TOKENS * DD * 2;
  __hip_bfloat16* w1t = (__hip_bfloat16*)ws;  ws += (size_t)EE * WW * DD * 2;
  __hip_bfloat16* w2t = (__hip_bfloat16*)ws;  ws += (size_t)EE * DD * WW * 2;
  __hip_bfloat16* act = (__hip_bfloat16*)ws;  ws += (size_t)EE * CAP * WW * 2;
  __hip_bfloat16* y   = (__hip_bfloat16*)ws;  ws += (size_t)EE * CAP * DD * 2;
  int*   counts = (int*)ws;                   ws += 256;
  int*   idx    = (int*)ws;                   ws += (size_t)EE * CAP * 4;
  int*   sel    = (int*)ws;                   ws += (size_t)T_TOKENS * 4;
  int*   tslot  = (int*)ws;                   ws += (size_t)T_TOKENS * 8;
  float* wpair  = (float*)ws;                 ws += (size_t)T_TOKENS * 8;

  // k1: w1 transpose (XCD-aligned, 512 blocks) + router
  pre_kernel<<<TR1_BLOCKS + T_TOKENS / 4, 256, 0, stream>>>(
      w1, x, rw, w1t, xb, sel, wpair);
  // k2: deterministic contention-free list build
  build_lists<<<1, 1024, 0, stream>>>(sel, counts, idx, tslot);
  // k3: w2 transpose (front, XCD-aligned) + grouped GEMM1
  gemm1_kernel<<<TR2_BLOCKS + GEMM_BLOCKS, 256, 0, stream>>>(
      xb, w1t, counts, idx, act, w2, w2t);
  // k4: grouped GEMM2
  gemm2_kernel<<<GEMM_BLOCKS, 256, 0, stream>>>(act, w2t, counts, y);
  // k5: weighted combine
  combine_kernel<<<T_TOKENS, 256, 0, stream>>>(y, tslot, wpair, out);
}

// Round 10
// 189.701 us; speedup vs baseline: 1.0677x; 1.0021x over previous
//
#include <hip/hip_runtime.h>
#include <hip/hip_bf16.h>

// MoE MLP (top-2 of 8 experts), T=4096 tokens, D=1024, W=1024.
// R16: consolidation. R15 confirmed XCD-aligned transposes make w1t/w2t reads
//      L2-local (gemm1 GEMM-part FETCH ~1MB) but GEMM runs at its structural
//      rate (~500 TF, on m102's curve for M=1024/expert). Remaining fat is
//      serial chain structure:
//      (1) k2 = {block 0: ballot build_lists} || {blocks 1-512: w2 transpose,
//          XCD-aligned e=bid&7} -- serial 7us list build hidden under the
//          BW-bound transpose (R9-proven merge, R15-proven alignment).
//      (2) gemm1 = pure 768-block GEMM (transpose front removed).
//      (3) combine grid-strided: 512 blocks x 8 tokens (was 4096 tiny blocks).
// Retained: 128x128 GEMM tile BK=64 granule-XOR swizzle (R8/R10-proven),
//           XCD-aligned w1t in pre, CAP=1536, gload_lds w16 staging.

#define T_TOKENS 4096
#define DD 1024
#define EE 8
#define WW 1024
#define CAP 1536              // per-expert capacity (expected ~1024, sigma ~28)
#define BM 128
#define BN 128
#define BK 64
#define MT (CAP / BM)         // 12 m-tiles max per expert
#define NT (WW / BN)          // 8 n-tiles
#define GEMM_BLOCKS (EE * MT * NT)  // 768
#define TR1_BLOCKS 512        // w1 transpose blocks (128x128 tiles, in pre)
#define TLD 132               // LDS transpose tile row stride (shorts), pad=4

typedef short bf16x8 __attribute__((ext_vector_type(8)));
typedef float f32x4 __attribute__((ext_vector_type(4)));

__device__ __forceinline__ void gload_lds16(const void* g, void* l) {
  __builtin_amdgcn_global_load_lds((__attribute__((address_space(1))) void*)(g),
                                   (__attribute__((address_space(3))) void*)(l),
                                   16, 0, 0);
}

__device__ __forceinline__ float bf2f(unsigned short u) {
  union { unsigned int i; float f; } v; v.i = (unsigned int)u << 16; return v.f;
}

__device__ __forceinline__ unsigned short f2bf_u(float f) {
  __hip_bfloat16 h = __float2bfloat16(f);
  union { __hip_bfloat16 h; unsigned short u; } c; c.h = h; return c.u;
}

// ---- 128x128 fp32->bf16 transpose tile through LDS, 256 threads (R10) ----
// dst[(c0+c)*dst_ld + r0 + r] = bf16(src[(r0+r)*src_ld + c0 + c])
__device__ __forceinline__ void transpose_tile_128(
    const float* __restrict__ src, long src_ld, long r0, long c0,
    unsigned short* __restrict__ dst, long dst_ld, unsigned short* lds)
{
  int tid = threadIdx.x;
  int cq = tid & 31;            // covers 4 src cols
  int rb = tid >> 5;            // row base 0..7
#pragma unroll
  for (int i = 0; i < 16; i++) {
    int r = rb + i * 8;
    f32x4 v = *(const f32x4*)(src + (r0 + r) * src_ld + c0 + cq * 4);
#pragma unroll
    for (int j = 0; j < 4; j++)
      lds[(cq * 4 + j) * TLD + r] = f2bf_u(v[j]);
  }
  __syncthreads();
#pragma unroll
  for (int it = 0; it < 8; it++) {
    int slot = it * 256 + tid;
    int c = slot >> 4;          // dst row within tile
    int m = slot & 15;          // 8-elem chunk within row
    const unsigned short* p = lds + (size_t)c * TLD + m * 8;
    uint2 lo = *(const uint2*)(p);
    uint2 hi = *(const uint2*)(p + 4);
    uint4 o; o.x = lo.x; o.y = lo.y; o.z = hi.x; o.w = hi.y;
    *(uint4*)(dst + (c0 + c) * dst_ld + r0 + m * 8) = o;
  }
}

// ---------------- pre: w1 transpose (XCD-aligned) + router ----------------
// blocks [0,512): w1 transpose, expert slab = b&7 (matches gemm1's XCD map);
// blocks [512,1536): router, 1 wave = 1 token.
__global__ __launch_bounds__(256) void pre_kernel(
    const float* __restrict__ w1, const float* __restrict__ x,
    const float* __restrict__ rw,
    __hip_bfloat16* __restrict__ w1t, __hip_bfloat16* __restrict__ xb,
    int* __restrict__ sel, float* __restrict__ wpair)
{
  __shared__ unsigned short lds_t[128 * TLD];   // 33792 B
  int b = blockIdx.x;
  if (b < TR1_BLOCKS) {
    // w1 [D=1024, E*W=8192] -> w1t [8192, 1024] bf16; expert e = b&7 so the
    // producer block sits on the same XCD as gemm1's consumer blocks.
    int e = b & 7;
    int t = b >> 3;             // 0..63
    int bn = e * 8 + (t >> 3);  // dst row tile (expert slab rows e*1024..)
    int bd = t & 7;             // dst col tile
    transpose_tile_128(w1, EE * WW, (long)bd * 128, (long)bn * 128,
                       (unsigned short*)w1t, DD, lds_t);
  } else {
    // router: one wave per token, fp32 logits, top-2, no atomics
    int lane = threadIdx.x & 63;
    int wave = threadIdx.x >> 6;
    int t = (b - TR1_BLOCKS) * 4 + wave;
    const float* xrow = x + (size_t)t * DD;
    float acc[EE];
#pragma unroll
    for (int e = 0; e < EE; e++) acc[e] = 0.f;
#pragma unroll
    for (int i = 0; i < DD / 64; i++) {
      int d = lane + i * 64;
      float xv = xrow[d];
      xb[t * DD + d] = __float2bfloat16(xv);   // fused x -> bf16
#pragma unroll
      for (int e = 0; e < EE; e++) acc[e] += xv * rw[e * DD + d];
    }
#pragma unroll
    for (int e = 0; e < EE; e++) {
#pragma unroll
      for (int off = 32; off > 0; off >>= 1)
        acc[e] += __shfl_down(acc[e], off, 64);
    }
    if (lane == 0) {
      float p[EE];
#pragma unroll
      for (int e = 0; e < EE; e++) p[e] = 1.f / (1.f + expf(-acc[e]));
      // top-2, ties -> lowest index (matches jax.lax.top_k stable ordering)
      int e0 = 0; float b0 = p[0];
      for (int e = 1; e < EE; e++) if (p[e] > b0) { b0 = p[e]; e0 = e; }
      int e1 = -1; float b1 = -1.f;
      for (int e = 0; e < EE; e++) {
        if (e == e0) continue;
        if (p[e] > b1) { b1 = p[e]; e1 = e; }
      }
      float s = b0 + b1 + 1e-20f;
      sel[t] = e0 | (e1 << 8);
      wpair[2 * t]     = b0 / s;
      wpair[2 * t + 1] = b1 / s;
    }
  }
}

// ------- k2: block 0 = ballot list build; blocks 1..512 = w2 transpose ------
// 1024 threads. List build (serial ~7us) hides under the BW-bound transpose.
// w2t XCD alignment: e = bid&7 -> producer XCD = consumer XCD (gemm2).
__global__ __launch_bounds__(1024) void lists_w2t_kernel(
    const int* __restrict__ sel, int* __restrict__ counts,
    int* __restrict__ idx, int* __restrict__ tslot,
    const float* __restrict__ w2, __hip_bfloat16* __restrict__ w2t)
{
  __shared__ __attribute__((aligned(16))) unsigned short lds_t[128 * TLD];
  __shared__ int lcnt[EE];
  int bid = blockIdx.x;
  int tid = threadIdx.x;
  if (bid == 0) {
    // ---- build per-expert token lists (exact R8 ballot logic) ----
    int lane = tid & 63;
    if (tid < EE) lcnt[tid] = 0;
    __syncthreads();
    unsigned long long lower = (1ull << lane) - 1;
#pragma unroll
    for (int j = 0; j < T_TOKENS / 1024; j++) {
      int t = j * 1024 + tid;
      int s = sel[t];
      int e0 = s & 0xff, e1 = (s >> 8) & 0xff;
      int slot0 = 0, slot1 = 0;
#pragma unroll
      for (int e = 0; e < EE; e++) {
        unsigned long long m0 = __ballot(e0 == e);
        unsigned long long m1 = __ballot(e1 == e);
        int c0 = __popcll(m0), c1 = __popcll(m1);
        int base = 0;
        if (lane == 0 && (c0 + c1) > 0) base = atomicAdd(&lcnt[e], c0 + c1);
        base = __shfl(base, 0, 64);
        if (e0 == e) slot0 = base + __popcll(m0 & lower);
        if (e1 == e) slot1 = base + c0 + __popcll(m1 & lower);
      }
      int p0 = e0 * CAP + slot0, p1 = e1 * CAP + slot1;
      idx[p0] = t; idx[p1] = t;
      tslot[2 * t] = p0; tslot[2 * t + 1] = p1;
    }
    __syncthreads();
    if (tid < EE) counts[tid] = lcnt[tid];
  } else {
    // ---- w2 transpose: expert slice [W,D] -> w2t[e] [D,W], e = bid&7 ----
    // For each e, the 64 blocks with bid%8==e (bid in 1..512) enumerate
    // t2 = (bid-1)>>3 = 0..63 distinct tiles.
    int e = bid & 7;
    int t2 = (bid - 1) >> 3;        // 0..63
    const float* src = w2 + (long)e * WW * DD;
    unsigned short* dst = (unsigned short*)(w2t + (long)e * DD * WW);
    long r0 = (long)(t2 >> 3) * 128;   // W dim (src row / dst col)
    long c0 = (long)(t2 & 7) * 128;    // D dim (src col / dst row)
    // 1024-thread variant of transpose_tile_128
    int cq = tid & 31;            // 4 src cols
    int row = tid >> 5;           // 0..31
#pragma unroll
    for (int i = 0; i < 4; i++) {
      int r = row + i * 32;
      f32x4 v = *(const f32x4*)(src + (r0 + r) * DD + c0 + cq * 4);
#pragma unroll
      for (int j = 0; j < 4; j++)
        lds_t[(cq * 4 + j) * TLD + r] = f2bf_u(v[j]);
    }
    __syncthreads();
#pragma unroll
    for (int it = 0; it < 2; it++) {
      int slot = it * 1024 + tid;
      int c = slot >> 4;          // dst row within tile
      int m = slot & 15;          // 8-elem chunk within row
      const unsigned short* p = lds_t + (size_t)c * TLD + m * 8;
      uint2 lo = *(const uint2*)(p);
      uint2 hi = *(const uint2*)(p + 4);
      uint4 o; o.x = lo.x; o.y = lo.y; o.z = hi.x; o.w = hi.y;
      *(uint4*)(dst + (c0 + c) * WW + r0 + m * 8) = o;
    }
  }
}

// ---------------- grouped GEMM1: act = relu(gather(xb) @ W1_e)^2 ------------
// 768 blocks, 128x128 tile, BK=64. XCD map: expert = bid & 7.
__global__ __launch_bounds__(256, 3) void gemm1_kernel(
    const __hip_bfloat16* __restrict__ xb, const __hip_bfloat16* __restrict__ w1t,
    const int* __restrict__ counts, const int* __restrict__ idx,
    __hip_bfloat16* __restrict__ act)
{
  __shared__ __attribute__((aligned(16))) char smem[32768];
  short* As = (short*)smem;
  short* Bs = (short*)(smem + 16384);
  int bid = blockIdx.x;
  int e = bid & 7;
  int i = bid >> 3;
  int mt = i >> 3, nt = i & 7;
  int n_e = counts[e];
  if (mt * BM >= n_e) return;

  int tid = threadIdx.x;
  int lane = tid & 63;
  int wave = __builtin_amdgcn_readfirstlane(tid >> 6);
  int wm = (wave >> 1) * 64, wn = (wave & 1) * 64;
  int m16 = lane & 15, qd = lane >> 4;

  // staging: granule = 16B (8 bf16); 8 granule-cols/row; slot s -> row s>>3,
  // swizzled col (s&7)^(r&7); LDS dest linear (gload_lds is base+lane*16).
  const __hip_bfloat16* gA[4];
  const __hip_bfloat16* gB[4];
#pragma unroll
  for (int i2 = 0; i2 < 4; i2++) {
    int s = i2 * 256 + tid;
    int r = s >> 3;
    int q = (s & 7) ^ (r & 7);
    int rowA = mt * BM + r;
    int slot = rowA < n_e ? rowA : n_e - 1;   // clamp tail rows to valid slot
    int tok = idx[e * CAP + slot];
    gA[i2] = xb + (size_t)tok * DD + q * 8;
    gB[i2] = w1t + ((size_t)e * WW + nt * BN + r) * DD + q * 8;
  }
  short* ldsA[4];
  short* ldsB[4];
#pragma unroll
  for (int i2 = 0; i2 < 4; i2++) {
    ldsA[i2] = As + (i2 * 256 + wave * 64) * 8;
    ldsB[i2] = Bs + (i2 * 256 + wave * 64) * 8;
  }

  int aoff[4][2], boff[4][2];
#pragma unroll
  for (int mi = 0; mi < 4; mi++) {
    int r = wm + mi * 16 + m16;
#pragma unroll
    for (int h = 0; h < 2; h++)
      aoff[mi][h] = (r * 8 + ((qd + h * 4) ^ (r & 7))) * 8;
  }
#pragma unroll
  for (int ni = 0; ni < 4; ni++) {
    int r = wn + ni * 16 + m16;
#pragma unroll
    for (int h = 0; h < 2; h++)
      boff[ni][h] = (r * 8 + ((qd + h * 4) ^ (r & 7))) * 8;
  }

  f32x4 zero = {0.f, 0.f, 0.f, 0.f};
  f32x4 acc[4][4];
#pragma unroll
  for (int mi = 0; mi < 4; mi++)
#pragma unroll
    for (int ni = 0; ni < 4; ni++) acc[mi][ni] = zero;

  for (int k0 = 0; k0 < DD; k0 += BK) {
#pragma unroll
    for (int i2 = 0; i2 < 4; i2++) gload_lds16(gA[i2] + k0, ldsA[i2]);
#pragma unroll
    for (int i2 = 0; i2 < 4; i2++) gload_lds16(gB[i2] + k0, ldsB[i2]);
    __syncthreads();
#pragma unroll
    for (int h = 0; h < 2; h++) {
      bf16x8 af[4], bfr[4];
#pragma unroll
      for (int mi = 0; mi < 4; mi++) af[mi] = *(const bf16x8*)(As + aoff[mi][h]);
#pragma unroll
      for (int ni = 0; ni < 4; ni++) bfr[ni] = *(const bf16x8*)(Bs + boff[ni][h]);
#pragma unroll
      for (int mi = 0; mi < 4; mi++)
#pragma unroll
        for (int ni = 0; ni < 4; ni++)
          acc[mi][ni] = __builtin_amdgcn_mfma_f32_16x16x32_bf16(
              af[mi], bfr[ni], acc[mi][ni], 0, 0, 0);
    }
    __syncthreads();
  }

  // epilogue: relu^2 -> bf16 act[(e*CAP + slot)][col]
#pragma unroll
  for (int mi = 0; mi < 4; mi++) {
#pragma unroll
    for (int reg = 0; reg < 4; reg++) {
      int rowt = mt * BM + wm + mi * 16 + qd * 4 + reg;
      if (rowt < n_e) {
#pragma unroll
        for (int ni = 0; ni < 4; ni++) {
          float v = acc[mi][ni][reg];
          v = v > 0.f ? v * v : 0.f;
          int col = nt * BN + wn + ni * 16 + m16;
          act[((size_t)e * CAP + rowt) * WW + col] = __float2bfloat16(v);
        }
      }
    }
  }
}

// ---------------- grouped GEMM2: y = act @ W2_e (raw bf16 y) ----------------
__global__ __launch_bounds__(256, 3) void gemm2_kernel(
    const __hip_bfloat16* __restrict__ act, const __hip_bfloat16* __restrict__ w2t,
    const int* __restrict__ counts, __hip_bfloat16* __restrict__ y)
{
  __shared__ __attribute__((aligned(16))) char smem[32768];
  short* As = (short*)smem;
  short* Bs = (short*)(smem + 16384);
  int bid = blockIdx.x;
  int e = bid & 7;
  int i = bid >> 3;
  int mt = i >> 3, nt = i & 7;
  int n_e = counts[e];
  if (mt * BM >= n_e) return;

  int tid = threadIdx.x;
  int lane = tid & 63;
  int wave = __builtin_amdgcn_readfirstlane(tid >> 6);
  int wm = (wave >> 1) * 64, wn = (wave & 1) * 64;
  int m16 = lane & 15, qd = lane >> 4;

  const __hip_bfloat16* gA[4];
  const __hip_bfloat16* gB[4];
#pragma unroll
  for (int i2 = 0; i2 < 4; i2++) {
    int s = i2 * 256 + tid;
    int r = s >> 3;
    int q = (s & 7) ^ (r & 7);
    // rows >= n_e: poison bytes, but row-isolated in MFMA -> discarded rows only
    gA[i2] = act + ((size_t)e * CAP + mt * BM + r) * WW + q * 8;
    gB[i2] = w2t + ((size_t)e * DD + nt * BN + r) * WW + q * 8;
  }
  short* ldsA[4];
  short* ldsB[4];
#pragma unroll
  for (int i2 = 0; i2 < 4; i2++) {
    ldsA[i2] = As + (i2 * 256 + wave * 64) * 8;
    ldsB[i2] = Bs + (i2 * 256 + wave * 64) * 8;
  }

  int aoff[4][2], boff[4][2];
#pragma unroll
  for (int mi = 0; mi < 4; mi++) {
    int r = wm + mi * 16 + m16;
#pragma unroll
    for (int h = 0; h < 2; h++)
      aoff[mi][h] = (r * 8 + ((qd + h * 4) ^ (r & 7))) * 8;
  }
#pragma unroll
  for (int ni = 0; ni < 4; ni++) {
    int r = wn + ni * 16 + m16;
#pragma unroll
    for (int h = 0; h < 2; h++)
      boff[ni][h] = (r * 8 + ((qd + h * 4) ^ (r & 7))) * 8;
  }

  f32x4 zero = {0.f, 0.f, 0.f, 0.f};
  f32x4 acc[4][4];
#pragma unroll
  for (int mi = 0; mi < 4; mi++)
#pragma unroll
    for (int ni = 0; ni < 4; ni++) acc[mi][ni] = zero;

  for (int k0 = 0; k0 < WW; k0 += BK) {
#pragma unroll
    for (int i2 = 0; i2 < 4; i2++) gload_lds16(gA[i2] + k0, ldsA[i2]);
#pragma unroll
    for (int i2 = 0; i2 < 4; i2++) gload_lds16(gB[i2] + k0, ldsB[i2]);
    __syncthreads();
#pragma unroll
    for (int h = 0; h < 2; h++) {
      bf16x8 af[4], bfr[4];
#pragma unroll
      for (int mi = 0; mi < 4; mi++) af[mi] = *(const bf16x8*)(As + aoff[mi][h]);
#pragma unroll
      for (int ni = 0; ni < 4; ni++) bfr[ni] = *(const bf16x8*)(Bs + boff[ni][h]);
#pragma unroll
      for (int mi = 0; mi < 4; mi++)
#pragma unroll
        for (int ni = 0; ni < 4; ni++)
          acc[mi][ni] = __builtin_amdgcn_mfma_f32_16x16x32_bf16(
              af[mi], bfr[ni], acc[mi][ni], 0, 0, 0);
    }
    __syncthreads();
  }

  // epilogue: raw y (routing weights applied in combine)
#pragma unroll
  for (int mi = 0; mi < 4; mi++) {
#pragma unroll
    for (int reg = 0; reg < 4; reg++) {
      int slot = mt * BM + wm + mi * 16 + qd * 4 + reg;
      if (slot < n_e) {
#pragma unroll
        for (int ni = 0; ni < 4; ni++) {
          int col = nt * BN + wn + ni * 16 + m16;
          y[((size_t)e * CAP + slot) * DD + col] = __float2bfloat16(acc[mi][ni][reg]);
        }
      }
    }
  }
}

// ---------------- combine: out[t] = w0*y[slot0] + w1*y[slot1] ----------------
// 512 blocks, grid-stride over 4096 tokens (8 per block).
__global__ __launch_bounds__(256) void combine_kernel(
    const __hip_bfloat16* __restrict__ y, const int* __restrict__ tslot,
    const float* __restrict__ wpair, float* __restrict__ out)
{
  int c = threadIdx.x * 4;
  for (int t = blockIdx.x; t < T_TOKENS; t += 512) {
    int s0 = tslot[2 * t], s1 = tslot[2 * t + 1];
    float w0 = wpair[2 * t], w1 = wpair[2 * t + 1];
    const unsigned short* yu = (const unsigned short*)y;
    ushort4 a = *(const ushort4*)(yu + (size_t)s0 * DD + c);
    ushort4 bq = *(const ushort4*)(yu + (size_t)s1 * DD + c);
    f32x4 o;
    o[0] = w0 * bf2f(a.x) + w1 * bf2f(bq.x);
    o[1] = w0 * bf2f(a.y) + w1 * bf2f(bq.y);
    o[2] = w0 * bf2f(a.z) + w1 * bf2f(bq.z);
    o[3] = w0 * bf2f(a.w) + w1 * bf2f(bq.w);
    *(f32x4*)(out + (size_t)t * DD + c) = o;
  }
}

extern "C" void kernel_launch(void* const* d_in, const int* in_sizes, int n_in,
                              void* d_out, int out_size, void* d_ws, size_t ws_size,
                              hipStream_t stream)
{
  const float* x  = (const float*)d_in[0];
  const float* rw = (const float*)d_in[1];
  const float* w1 = (const float*)d_in[2];
  const float* w2 = (const float*)d_in[3];
  float* out = (float*)d_out;

  char* ws = (char*)d_ws;
  __hip_bfloat16* xb  = (__hip_bfloat16*)ws;  ws += (size_t)T_TOKENS * DD * 2;
  __hip_bfloat16* w1t = (__hip_bfloat16*)ws;  ws += (size_t)EE * WW * DD * 2;
  __hip_bfloat16* w2t = (__hip_bfloat16*)ws;  ws += (size_t)EE * DD * WW * 2;
  __hip_bfloat16* act = (__hip_bfloat16*)ws;  ws += (size_t)EE * CAP * WW * 2;
  __hip_bfloat16* y   = (__hip_bfloat16*)ws;  ws += (size_t)EE * CAP * DD * 2;
  int*   counts = (int*)ws;                   ws += 256;
  int*   idx    = (int*)ws;                   ws += (size_t)EE * CAP * 4;
  int*   sel    = (int*)ws;                   ws += (size_t)T_TOKENS * 4;
  int*   tslot  = (int*)ws;                   ws += (size_t)T_TOKENS * 8;
  float* wpair  = (float*)ws;                 ws += (size_t)T_TOKENS * 8;

  // k1: w1 transpose (XCD-aligned, 512 blocks) + router
  pre_kernel<<<TR1_BLOCKS + T_TOKENS / 4, 256, 0, stream>>>(
      w1, x, rw, w1t, xb, sel, wpair);
  // k2: list build (block 0) hidden under w2 transpose (blocks 1..512)
  lists_w2t_kernel<<<513, 1024, 0, stream>>>(sel, counts, idx, tslot, w2, w2t);
  // k3: grouped GEMM1 (pure, 768 blocks)
  gemm1_kernel<<<GEMM_BLOCKS, 256, 0, stream>>>(xb, w1t, counts, idx, act);
  // k4: grouped GEMM2
  gemm2_kernel<<<GEMM_BLOCKS, 256, 0, stream>>>(act, w2t, counts, y);
  // k5: weighted combine (grid-stride, 512 blocks)
  combine_kernel<<<512, 256, 0, stream>>>(y, tslot, wpair, out);
}

// Round 11
// 189.236 us; speedup vs baseline: 1.0703x; 1.0025x over previous
//
#include <hip/hip_runtime.h>
#include <hip/hip_bf16.h>

// MoE MLP (top-2 of 8 experts), T=4096 tokens, D=1024, W=1024.
// R17: R16 frame + VECTORIZED ROUTER (the one measured-slow untouched phase:
//      R7 profile showed pre @26% occ, 8.7% VALUBusy -> router is issue-bound
//      scalar code; 8 scalar rw loads/lane/iter). Now f32x4 x + f32x4 rw +
//      packed ushort4 xb stores: 4 iters instead of 16, ~3.5x fewer issues.
// Frame (all proven neutral-or-better): XCD-aligned w1t in pre (R15),
//      k2 = {blk0 ballot lists || blks 1-512 w2t XCD-aligned} (R16),
//      pure 768-blk gemm1 / gemm2 (128x128, BK=64, granule-XOR swizzle,
//      R8/R10-proven), grid-strided combine (R16), CAP=1536, gload_lds w16.

#define T_TOKENS 4096
#define DD 1024
#define EE 8
#define WW 1024
#define CAP 1536              // per-expert capacity (expected ~1024, sigma ~28)
#define BM 128
#define BN 128
#define BK 64
#define MT (CAP / BM)         // 12 m-tiles max per expert
#define NT (WW / BN)          // 8 n-tiles
#define GEMM_BLOCKS (EE * MT * NT)  // 768
#define TR1_BLOCKS 512        // w1 transpose blocks (128x128 tiles, in pre)
#define TLD 132               // LDS transpose tile row stride (shorts), pad=4

typedef short bf16x8 __attribute__((ext_vector_type(8)));
typedef float f32x4 __attribute__((ext_vector_type(4)));

__device__ __forceinline__ void gload_lds16(const void* g, void* l) {
  __builtin_amdgcn_global_load_lds((__attribute__((address_space(1))) void*)(g),
                                   (__attribute__((address_space(3))) void*)(l),
                                   16, 0, 0);
}

__device__ __forceinline__ float bf2f(unsigned short u) {
  union { unsigned int i; float f; } v; v.i = (unsigned int)u << 16; return v.f;
}

__device__ __forceinline__ unsigned short f2bf_u(float f) {
  __hip_bfloat16 h = __float2bfloat16(f);
  union { __hip_bfloat16 h; unsigned short u; } c; c.h = h; return c.u;
}

// ---- 128x128 fp32->bf16 transpose tile through LDS, 256 threads (R10) ----
// dst[(c0+c)*dst_ld + r0 + r] = bf16(src[(r0+r)*src_ld + c0 + c])
__device__ __forceinline__ void transpose_tile_128(
    const float* __restrict__ src, long src_ld, long r0, long c0,
    unsigned short* __restrict__ dst, long dst_ld, unsigned short* lds)
{
  int tid = threadIdx.x;
  int cq = tid & 31;            // covers 4 src cols
  int rb = tid >> 5;            // row base 0..7
#pragma unroll
  for (int i = 0; i < 16; i++) {
    int r = rb + i * 8;
    f32x4 v = *(const f32x4*)(src + (r0 + r) * src_ld + c0 + cq * 4);
#pragma unroll
    for (int j = 0; j < 4; j++)
      lds[(cq * 4 + j) * TLD + r] = f2bf_u(v[j]);
  }
  __syncthreads();
#pragma unroll
  for (int it = 0; it < 8; it++) {
    int slot = it * 256 + tid;
    int c = slot >> 4;          // dst row within tile
    int m = slot & 15;          // 8-elem chunk within row
    const unsigned short* p = lds + (size_t)c * TLD + m * 8;
    uint2 lo = *(const uint2*)(p);
    uint2 hi = *(const uint2*)(p + 4);
    uint4 o; o.x = lo.x; o.y = lo.y; o.z = hi.x; o.w = hi.y;
    *(uint4*)(dst + (c0 + c) * dst_ld + r0 + m * 8) = o;
  }
}

// ---------------- pre: w1 transpose (XCD-aligned) + vectorized router -------
// blocks [0,512): w1 transpose, expert slab = b&7 (matches gemm1's XCD map);
// blocks [512,1536): router, 1 wave = 1 token, f32x4 loads.
__global__ __launch_bounds__(256) void pre_kernel(
    const float* __restrict__ w1, const float* __restrict__ x,
    const float* __restrict__ rw,
    __hip_bfloat16* __restrict__ w1t, __hip_bfloat16* __restrict__ xb,
    int* __restrict__ sel, float* __restrict__ wpair)
{
  __shared__ unsigned short lds_t[128 * TLD];   // 33792 B
  int b = blockIdx.x;
  if (b < TR1_BLOCKS) {
    // w1 [D=1024, E*W=8192] -> w1t [8192, 1024] bf16; expert e = b&7 so the
    // producer block sits on the same XCD as gemm1's consumer blocks.
    int e = b & 7;
    int t = b >> 3;             // 0..63
    int bn = e * 8 + (t >> 3);  // dst row tile (expert slab rows e*1024..)
    int bd = t & 7;             // dst col tile
    transpose_tile_128(w1, EE * WW, (long)bd * 128, (long)bn * 128,
                       (unsigned short*)w1t, DD, lds_t);
  } else {
    // router: one wave per token, f32x4 x / rw loads, packed bf16x4 stores
    int lane = threadIdx.x & 63;
    int wave = threadIdx.x >> 6;
    int t = (b - TR1_BLOCKS) * 4 + wave;
    const float* xrow = x + (size_t)t * DD;
    unsigned short* xbrow = (unsigned short*)xb + (size_t)t * DD;
    float acc[EE];
#pragma unroll
    for (int e = 0; e < EE; e++) acc[e] = 0.f;
#pragma unroll
    for (int i = 0; i < DD / 256; i++) {        // 4 iterations
      int d = lane * 4 + i * 256;
      f32x4 xv = *(const f32x4*)(xrow + d);
      union { unsigned short u[4]; ushort4 v; } pk;
#pragma unroll
      for (int j = 0; j < 4; j++) pk.u[j] = f2bf_u(xv[j]);
      *(ushort4*)(xbrow + d) = pk.v;            // fused x -> bf16
#pragma unroll
      for (int e = 0; e < EE; e++) {
        f32x4 rv = *(const f32x4*)(rw + e * DD + d);
        acc[e] += xv[0] * rv[0] + xv[1] * rv[1] + xv[2] * rv[2] + xv[3] * rv[3];
      }
    }
#pragma unroll
    for (int e = 0; e < EE; e++) {
#pragma unroll
      for (int off = 32; off > 0; off >>= 1)
        acc[e] += __shfl_down(acc[e], off, 64);
    }
    if (lane == 0) {
      float p[EE];
#pragma unroll
      for (int e = 0; e < EE; e++) p[e] = 1.f / (1.f + expf(-acc[e]));
      // top-2, ties -> lowest index (matches jax.lax.top_k stable ordering)
      int e0 = 0; float b0 = p[0];
      for (int e = 1; e < EE; e++) if (p[e] > b0) { b0 = p[e]; e0 = e; }
      int e1 = -1; float b1 = -1.f;
      for (int e = 0; e < EE; e++) {
        if (e == e0) continue;
        if (p[e] > b1) { b1 = p[e]; e1 = e; }
      }
      float s = b0 + b1 + 1e-20f;
      sel[t] = e0 | (e1 << 8);
      wpair[2 * t]     = b0 / s;
      wpair[2 * t + 1] = b1 / s;
    }
  }
}

// ------- k2: block 0 = ballot list build; blocks 1..512 = w2 transpose ------
// 1024 threads. List build (serial ~7us) hides under the BW-bound transpose.
// w2t XCD alignment: e = bid&7 -> producer XCD = consumer XCD (gemm2).
__global__ __launch_bounds__(1024) void lists_w2t_kernel(
    const int* __restrict__ sel, int* __restrict__ counts,
    int* __restrict__ idx, int* __restrict__ tslot,
    const float* __restrict__ w2, __hip_bfloat16* __restrict__ w2t)
{
  __shared__ __attribute__((aligned(16))) unsigned short lds_t[128 * TLD];
  __shared__ int lcnt[EE];
  int bid = blockIdx.x;
  int tid = threadIdx.x;
  if (bid == 0) {
    // ---- build per-expert token lists (exact R8 ballot logic) ----
    int lane = tid & 63;
    if (tid < EE) lcnt[tid] = 0;
    __syncthreads();
    unsigned long long lower = (1ull << lane) - 1;
#pragma unroll
    for (int j = 0; j < T_TOKENS / 1024; j++) {
      int t = j * 1024 + tid;
      int s = sel[t];
      int e0 = s & 0xff, e1 = (s >> 8) & 0xff;
      int slot0 = 0, slot1 = 0;
#pragma unroll
      for (int e = 0; e < EE; e++) {
        unsigned long long m0 = __ballot(e0 == e);
        unsigned long long m1 = __ballot(e1 == e);
        int c0 = __popcll(m0), c1 = __popcll(m1);
        int base = 0;
        if (lane == 0 && (c0 + c1) > 0) base = atomicAdd(&lcnt[e], c0 + c1);
        base = __shfl(base, 0, 64);
        if (e0 == e) slot0 = base + __popcll(m0 & lower);
        if (e1 == e) slot1 = base + c0 + __popcll(m1 & lower);
      }
      int p0 = e0 * CAP + slot0, p1 = e1 * CAP + slot1;
      idx[p0] = t; idx[p1] = t;
      tslot[2 * t] = p0; tslot[2 * t + 1] = p1;
    }
    __syncthreads();
    if (tid < EE) counts[tid] = lcnt[tid];
  } else {
    // ---- w2 transpose: expert slice [W,D] -> w2t[e] [D,W], e = bid&7 ----
    int e = bid & 7;
    int t2 = (bid - 1) >> 3;        // 0..63
    const float* src = w2 + (long)e * WW * DD;
    unsigned short* dst = (unsigned short*)(w2t + (long)e * DD * WW);
    long r0 = (long)(t2 >> 3) * 128;   // W dim (src row / dst col)
    long c0 = (long)(t2 & 7) * 128;    // D dim (src col / dst row)
    // 1024-thread variant of transpose_tile_128
    int cq = tid & 31;            // 4 src cols
    int row = tid >> 5;           // 0..31
#pragma unroll
    for (int i = 0; i < 4; i++) {
      int r = row + i * 32;
      f32x4 v = *(const f32x4*)(src + (r0 + r) * DD + c0 + cq * 4);
#pragma unroll
      for (int j = 0; j < 4; j++)
        lds_t[(cq * 4 + j) * TLD + r] = f2bf_u(v[j]);
    }
    __syncthreads();
#pragma unroll
    for (int it = 0; it < 2; it++) {
      int slot = it * 1024 + tid;
      int c = slot >> 4;          // dst row within tile
      int m = slot & 15;          // 8-elem chunk within row
      const unsigned short* p = lds_t + (size_t)c * TLD + m * 8;
      uint2 lo = *(const uint2*)(p);
      uint2 hi = *(const uint2*)(p + 4);
      uint4 o; o.x = lo.x; o.y = lo.y; o.z = hi.x; o.w = hi.y;
      *(uint4*)(dst + (c0 + c) * WW + r0 + m * 8) = o;
    }
  }
}

// ---------------- grouped GEMM1: act = relu(gather(xb) @ W1_e)^2 ------------
// 768 blocks, 128x128 tile, BK=64. XCD map: expert = bid & 7.
__global__ __launch_bounds__(256, 3) void gemm1_kernel(
    const __hip_bfloat16* __restrict__ xb, const __hip_bfloat16* __restrict__ w1t,
    const int* __restrict__ counts, const int* __restrict__ idx,
    __hip_bfloat16* __restrict__ act)
{
  __shared__ __attribute__((aligned(16))) char smem[32768];
  short* As = (short*)smem;
  short* Bs = (short*)(smem + 16384);
  int bid = blockIdx.x;
  int e = bid & 7;
  int i = bid >> 3;
  int mt = i >> 3, nt = i & 7;
  int n_e = counts[e];
  if (mt * BM >= n_e) return;

  int tid = threadIdx.x;
  int lane = tid & 63;
  int wave = __builtin_amdgcn_readfirstlane(tid >> 6);
  int wm = (wave >> 1) * 64, wn = (wave & 1) * 64;
  int m16 = lane & 15, qd = lane >> 4;

  // staging: granule = 16B (8 bf16); 8 granule-cols/row; slot s -> row s>>3,
  // swizzled col (s&7)^(r&7); LDS dest linear (gload_lds is base+lane*16).
  const __hip_bfloat16* gA[4];
  const __hip_bfloat16* gB[4];
#pragma unroll
  for (int i2 = 0; i2 < 4; i2++) {
    int s = i2 * 256 + tid;
    int r = s >> 3;
    int q = (s & 7) ^ (r & 7);
    int rowA = mt * BM + r;
    int slot = rowA < n_e ? rowA : n_e - 1;   // clamp tail rows to valid slot
    int tok = idx[e * CAP + slot];
    gA[i2] = xb + (size_t)tok * DD + q * 8;
    gB[i2] = w1t + ((size_t)e * WW + nt * BN + r) * DD + q * 8;
  }
  short* ldsA[4];
  short* ldsB[4];
#pragma unroll
  for (int i2 = 0; i2 < 4; i2++) {
    ldsA[i2] = As + (i2 * 256 + wave * 64) * 8;
    ldsB[i2] = Bs + (i2 * 256 + wave * 64) * 8;
  }

  int aoff[4][2], boff[4][2];
#pragma unroll
  for (int mi = 0; mi < 4; mi++) {
    int r = wm + mi * 16 + m16;
#pragma unroll
    for (int h = 0; h < 2; h++)
      aoff[mi][h] = (r * 8 + ((qd + h * 4) ^ (r & 7))) * 8;
  }
#pragma unroll
  for (int ni = 0; ni < 4; ni++) {
    int r = wn + ni * 16 + m16;
#pragma unroll
    for (int h = 0; h < 2; h++)
      boff[ni][h] = (r * 8 + ((qd + h * 4) ^ (r & 7))) * 8;
  }

  f32x4 zero = {0.f, 0.f, 0.f, 0.f};
  f32x4 acc[4][4];
#pragma unroll
  for (int mi = 0; mi < 4; mi++)
#pragma unroll
    for (int ni = 0; ni < 4; ni++) acc[mi][ni] = zero;

  for (int k0 = 0; k0 < DD; k0 += BK) {
#pragma unroll
    for (int i2 = 0; i2 < 4; i2++) gload_lds16(gA[i2] + k0, ldsA[i2]);
#pragma unroll
    for (int i2 = 0; i2 < 4; i2++) gload_lds16(gB[i2] + k0, ldsB[i2]);
    __syncthreads();
#pragma unroll
    for (int h = 0; h < 2; h++) {
      bf16x8 af[4], bfr[4];
#pragma unroll
      for (int mi = 0; mi < 4; mi++) af[mi] = *(const bf16x8*)(As + aoff[mi][h]);
#pragma unroll
      for (int ni = 0; ni < 4; ni++) bfr[ni] = *(const bf16x8*)(Bs + boff[ni][h]);
#pragma unroll
      for (int mi = 0; mi < 4; mi++)
#pragma unroll
        for (int ni = 0; ni < 4; ni++)
          acc[mi][ni] = __builtin_amdgcn_mfma_f32_16x16x32_bf16(
              af[mi], bfr[ni], acc[mi][ni], 0, 0, 0);
    }
    __syncthreads();
  }

  // epilogue: relu^2 -> bf16 act[(e*CAP + slot)][col]
#pragma unroll
  for (int mi = 0; mi < 4; mi++) {
#pragma unroll
    for (int reg = 0; reg < 4; reg++) {
      int rowt = mt * BM + wm + mi * 16 + qd * 4 + reg;
      if (rowt < n_e) {
#pragma unroll
        for (int ni = 0; ni < 4; ni++) {
          float v = acc[mi][ni][reg];
          v = v > 0.f ? v * v : 0.f;
          int col = nt * BN + wn + ni * 16 + m16;
          act[((size_t)e * CAP + rowt) * WW + col] = __float2bfloat16(v);
        }
      }
    }
  }
}

// ---------------- grouped GEMM2: y = act @ W2_e (raw bf16 y) ----------------
__global__ __launch_bounds__(256, 3) void gemm2_kernel(
    const __hip_bfloat16* __restrict__ act, const __hip_bfloat16* __restrict__ w2t,
    const int* __restrict__ counts, __hip_bfloat16* __restrict__ y)
{
  __shared__ __attribute__((aligned(16))) char smem[32768];
  short* As = (short*)smem;
  short* Bs = (short*)(smem + 16384);
  int bid = blockIdx.x;
  int e = bid & 7;
  int i = bid >> 3;
  int mt = i >> 3, nt = i & 7;
  int n_e = counts[e];
  if (mt * BM >= n_e) return;

  int tid = threadIdx.x;
  int lane = tid & 63;
  int wave = __builtin_amdgcn_readfirstlane(tid >> 6);
  int wm = (wave >> 1) * 64, wn = (wave & 1) * 64;
  int m16 = lane & 15, qd = lane >> 4;

  const __hip_bfloat16* gA[4];
  const __hip_bfloat16* gB[4];
#pragma unroll
  for (int i2 = 0; i2 < 4; i2++) {
    int s = i2 * 256 + tid;
    int r = s >> 3;
    int q = (s & 7) ^ (r & 7);
    // rows >= n_e: poison bytes, but row-isolated in MFMA -> discarded rows only
    gA[i2] = act + ((size_t)e * CAP + mt * BM + r) * WW + q * 8;
    gB[i2] = w2t + ((size_t)e * DD + nt * BN + r) * WW + q * 8;
  }
  short* ldsA[4];
  short* ldsB[4];
#pragma unroll
  for (int i2 = 0; i2 < 4; i2++) {
    ldsA[i2] = As + (i2 * 256 + wave * 64) * 8;
    ldsB[i2] = Bs + (i2 * 256 + wave * 64) * 8;
  }

  int aoff[4][2], boff[4][2];
#pragma unroll
  for (int mi = 0; mi < 4; mi++) {
    int r = wm + mi * 16 + m16;
#pragma unroll
    for (int h = 0; h < 2; h++)
      aoff[mi][h] = (r * 8 + ((qd + h * 4) ^ (r & 7))) * 8;
  }
#pragma unroll
  for (int ni = 0; ni < 4; ni++) {
    int r = wn + ni * 16 + m16;
#pragma unroll
    for (int h = 0; h < 2; h++)
      boff[ni][h] = (r * 8 + ((qd + h * 4) ^ (r & 7))) * 8;
  }

  f32x4 zero = {0.f, 0.f, 0.f, 0.f};
  f32x4 acc[4][4];
#pragma unroll
  for (int mi = 0; mi < 4; mi++)
#pragma unroll
    for (int ni = 0; ni < 4; ni++) acc[mi][ni] = zero;

  for (int k0 = 0; k0 < WW; k0 += BK) {
#pragma unroll
    for (int i2 = 0; i2 < 4; i2++) gload_lds16(gA[i2] + k0, ldsA[i2]);
#pragma unroll
    for (int i2 = 0; i2 < 4; i2++) gload_lds16(gB[i2] + k0, ldsB[i2]);
    __syncthreads();
#pragma unroll
    for (int h = 0; h < 2; h++) {
      bf16x8 af[4], bfr[4];
#pragma unroll
      for (int mi = 0; mi < 4; mi++) af[mi] = *(const bf16x8*)(As + aoff[mi][h]);
#pragma unroll
      for (int ni = 0; ni < 4; ni++) bfr[ni] = *(const bf16x8*)(Bs + boff[ni][h]);
#pragma unroll
      for (int mi = 0; mi < 4; mi++)
#pragma unroll
        for (int ni = 0; ni < 4; ni++)
          acc[mi][ni] = __builtin_amdgcn_mfma_f32_16x16x32_bf16(
              af[mi], bfr[ni], acc[mi][ni], 0, 0, 0);
    }
    __syncthreads();
  }

  // epilogue: raw y (routing weights applied in combine)
#pragma unroll
  for (int mi = 0; mi < 4; mi++) {
#pragma unroll
    for (int reg = 0; reg < 4; reg++) {
      int slot = mt * BM + wm + mi * 16 + qd * 4 + reg;
      if (slot < n_e) {
#pragma unroll
        for (int ni = 0; ni < 4; ni++) {
          int col = nt * BN + wn + ni * 16 + m16;
          y[((size_t)e * CAP + slot) * DD + col] = __float2bfloat16(acc[mi][ni][reg]);
        }
      }
    }
  }
}

// ---------------- combine: out[t] = w0*y[slot0] + w1*y[slot1] ----------------
// 512 blocks, grid-stride over 4096 tokens (8 per block).
__global__ __launch_bounds__(256) void combine_kernel(
    const __hip_bfloat16* __restrict__ y, const int* __restrict__ tslot,
    const float* __restrict__ wpair, float* __restrict__ out)
{
  int c = threadIdx.x * 4;
  for (int t = blockIdx.x; t < T_TOKENS; t += 512) {
    int s0 = tslot[2 * t], s1 = tslot[2 * t + 1];
    float w0 = wpair[2 * t], w1 = wpair[2 * t + 1];
    const unsigned short* yu = (const unsigned short*)y;
    ushort4 a = *(const ushort4*)(yu + (size_t)s0 * DD + c);
    ushort4 bq = *(const ushort4*)(yu + (size_t)s1 * DD + c);
    f32x4 o;
    o[0] = w0 * bf2f(a.x) + w1 * bf2f(bq.x);
    o[1] = w0 * bf2f(a.y) + w1 * bf2f(bq.y);
    o[2] = w0 * bf2f(a.z) + w1 * bf2f(bq.z);
    o[3] = w0 * bf2f(a.w) + w1 * bf2f(bq.w);
    *(f32x4*)(out + (size_t)t * DD + c) = o;
  }
}

extern "C" void kernel_launch(void* const* d_in, const int* in_sizes, int n_in,
                              void* d_out, int out_size, void* d_ws, size_t ws_size,
                              hipStream_t stream)
{
  const float* x  = (const float*)d_in[0];
  const float* rw = (const float*)d_in[1];
  const float* w1 = (const float*)d_in[2];
  const float* w2 = (const float*)d_in[3];
  float* out = (float*)d_out;

  char* ws = (char*)d_ws;
  __hip_bfloat16* xb  = (__hip_bfloat16*)ws;  ws += (size_t)T_TOKENS * DD * 2;
  __hip_bfloat16* w1t = (__hip_bfloat16*)ws;  ws += (size_t)EE * WW * DD * 2;
  __hip_bfloat16* w2t = (__hip_bfloat16*)ws;  ws += (size_t)EE * DD * WW * 2;
  __hip_bfloat16* act = (__hip_bfloat16*)ws;  ws += (size_t)EE * CAP * WW * 2;
  __hip_bfloat16* y   = (__hip_bfloat16*)ws;  ws += (size_t)EE * CAP * DD * 2;
  int*   counts = (int*)ws;                   ws += 256;
  int*   idx    = (int*)ws;                   ws += (size_t)EE * CAP * 4;
  int*   sel    = (int*)ws;                   ws += (size_t)T_TOKENS * 4;
  int*   tslot  = (int*)ws;                   ws += (size_t)T_TOKENS * 8;
  float* wpair  = (float*)ws;                 ws += (size_t)T_TOKENS * 8;

  // k1: w1 transpose (XCD-aligned, 512 blocks) + vectorized router
  pre_kernel<<<TR1_BLOCKS + T_TOKENS / 4, 256, 0, stream>>>(
      w1, x, rw, w1t, xb, sel, wpair);
  // k2: list build (block 0) hidden under w2 transpose (blocks 1..512)
  lists_w2t_kernel<<<513, 1024, 0, stream>>>(sel, counts, idx, tslot, w2, w2t);
  // k3: grouped GEMM1 (pure, 768 blocks)
  gemm1_kernel<<<GEMM_BLOCKS, 256, 0, stream>>>(xb, w1t, counts, idx, act);
  // k4: grouped GEMM2
  gemm2_kernel<<<GEMM_BLOCKS, 256, 0, stream>>>(act, w2t, counts, y);
  // k5: weighted combine (grid-stride, 512 blocks)
  combine_kernel<<<512, 256, 0, stream>>>(y, tslot, wpair, out);
}